// Round 1
// baseline (2207.246 us; speedup 1.0000x reference)
//
#include <hip/hip_runtime.h>
#include <stdint.h>

#define EPS 1e-5f
#define SLOPE 0.2f

// ---------------------------------------------------------------------------
// Mask dtype detection: mask may arrive as 1-byte bool or a 4-byte type
// (int32 / float32). In a 4-byte layout of 0/1 values, every byte at
// position i%4!=0 is 0 (int32) or in {0,0x80,0x3f} only at fixed slots
// (float32) -> bytes at i%4==1 are 0 for both. A random half-ones bool
// array has nonzero bytes everywhere. We scan only the first n bytes
// (n = element count), which is in-bounds for every candidate dtype.
// ---------------------------------------------------------------------------
__global__ void mask_detect_k(const uint8_t* __restrict__ raw, int nbytes,
                              unsigned* __restrict__ flag) {
  unsigned local = 0;
  for (int i = blockIdx.x * blockDim.x + threadIdx.x; i < nbytes;
       i += gridDim.x * blockDim.x)
    if (i & 3) local |= raw[i];
  if (local) atomicOr(flag, 1u);
}

__global__ void mask_convert_k(const uint8_t* __restrict__ raw,
                               const unsigned* __restrict__ flag,
                               uint8_t* __restrict__ m1, int n) {
  int i = blockIdx.x * blockDim.x + threadIdx.x;
  if (i >= n) return;
  uint8_t v;
  if (*flag) {
    v = raw[i];                       // 1-byte bool layout
  } else {                            // 4-byte layout (int32 or float32)
    size_t j = 4 * (size_t)i;
    v = (uint8_t)(raw[j] | raw[j + 1] | raw[j + 2] | raw[j + 3]);
  }
  m1[i] = v ? 1 : 0;
}

// mo[b,zo,yo,xo] = OR over 3x3x3 window at stride 2 (pad 1) of mi
__global__ void mask_down_k(const uint8_t* __restrict__ mi,
                            uint8_t* __restrict__ mo, int DIN) {
  int W = DIN >> 1;
  int id = blockIdx.x * blockDim.x + threadIdx.x;
  int total = 2 * W * W * W;
  if (id >= total) return;
  int xo = id % W; int t = id / W;
  int yo = t % W;  t /= W;
  int zo = t % W;  int b = t / W;
  int any = 0;
  for (int dz = 0; dz < 3; ++dz) {
    int z = 2 * zo + dz - 1; if (z < 0 || z >= DIN) continue;
    for (int dy = 0; dy < 3; ++dy) {
      int y = 2 * yo + dy - 1; if (y < 0 || y >= DIN) continue;
      for (int dx = 0; dx < 3; ++dx) {
        int x = 2 * xo + dx - 1; if (x < 0 || x >= DIN) continue;
        any |= mi[(((size_t)b * DIN + z) * DIN + y) * DIN + x];
      }
    }
  }
  mo[id] = any ? 1 : 0;
}

// w[Cout][K] -> wt[K][Cout]  (K = Cin*27), output-coalesced
__global__ void wtrans_k(const float* __restrict__ w, float* __restrict__ wt,
                         int COUT, int K) {
  int id = blockIdx.x * blockDim.x + threadIdx.x;
  if (id >= COUT * K) return;
  int c = id % COUT;
  int k = id / COUT;
  wt[id] = w[(size_t)c * K + k];
}

// ---------------------------------------------------------------------------
// Fused conv3d(3x3x3, pad 1, stride S) + LayerNorm(channel) + LeakyReLU + mask
// One output row (b, zo, yo, x=0..W-1) per workgroup. lane = output channel,
// wave w handles channels [64w, 64w+64). Input rows are wave-uniform (SGPRs),
// weights are per-lane VGPR loads from the transposed [Cin*27][Cout] layout.
// ---------------------------------------------------------------------------
template <int CIN, int COUT, int DIN, int S, bool MASK_IN>
__global__ __launch_bounds__(COUT) void conv_block(
    const float* __restrict__ in,        // [2][CIN][DIN][DIN][DIN]
    const float* __restrict__ wt,        // [CIN*27][COUT]
    const float* __restrict__ gamma,     // [COUT]
    const float* __restrict__ beta,      // [COUT]
    const uint8_t* __restrict__ min_,    // input-level mask [2][DIN^3] (MASK_IN)
    const uint8_t* __restrict__ mout,    // output-level mask [2][W^3]
    float* __restrict__ out)             // [2][COUT][W][W][W]
{
  constexpr int W  = DIN / S;   // output row length
  constexpr int CS = COUT / 64; // waves per workgroup
  constexpr int WP = W + 1;     // padded LDS row (odd stride, conflict-free)

  const int lane = threadIdx.x & 63;
  const int wave = threadIdx.x >> 6;
  const int c    = wave * 64 + lane;

  int bid = blockIdx.x;
  const int yo = bid % W; bid /= W;
  const int zo = bid % W; bid /= W;
  const int b  = bid;

  float acc[W];
#pragma unroll
  for (int v = 0; v < W; ++v) acc[v] = 0.f;

  for (int dz = 0; dz < 3; ++dz) {
    const int zin = S * zo + dz - 1;
    if (zin < 0 || zin >= DIN) continue;
    for (int dy = 0; dy < 3; ++dy) {
      const int yin = S * yo + dy - 1;
      if (yin < 0 || yin >= DIN) continue;
      const uint8_t* mrow =
          MASK_IN ? (min_ + ((size_t)b * DIN + zin) * DIN * DIN + (size_t)yin * DIN)
                  : nullptr;
      for (int ci = 0; ci < CIN; ++ci) {
        const float* rp =
            in + (((size_t)(b * CIN + ci) * DIN + zin) * DIN + yin) * DIN;
        // uniform input row with zero halo
        float xr[DIN + 2];
        xr[0] = 0.f; xr[DIN + 1] = 0.f;
#pragma unroll
        for (int i = 0; i < DIN; ++i) {
          float xv = rp[i];
          if (MASK_IN) xv = mrow[i] ? xv : 0.f;
          xr[i + 1] = xv;
        }
        // per-lane weights (coalesced: lane-consecutive channels)
        const float* wp = wt + (size_t)(((ci * 3 + dz) * 3 + dy) * 3) * COUT + c;
        const float w0 = wp[0];
        const float w1 = wp[COUT];
        const float w2 = wp[2 * COUT];
#pragma unroll
        for (int v = 0; v < W; ++v) {
          acc[v] += xr[S * v + 0] * w0;
          acc[v] += xr[S * v + 1] * w1;
          acc[v] += xr[S * v + 2] * w2;
        }
      }
    }
  }

  // ---- transpose raw conv tile through LDS ----
  __shared__ float ys[COUT * WP];
  __shared__ float redS[CS * W];
  __shared__ float redQ[CS * W];
#pragma unroll
  for (int v = 0; v < W; ++v) ys[c * WP + v] = acc[v];
  __syncthreads();

  // ---- LayerNorm over channels, per voxel ----
  constexpr int T   = 64 * CS;   // == COUT
  constexpr int G   = T / W;     // channel-groups per voxel
  constexpr int CPG = COUT / G;  // channels per thread
  const int v = threadIdx.x % W;
  const int g = threadIdx.x / W;

  float s = 0.f, sq = 0.f;
#pragma unroll
  for (int j = 0; j < CPG; ++j) {
    float val = ys[(g * CPG + j) * WP + v];
    s += val; sq += val * val;
  }
#pragma unroll
  for (int off = W; off < 64; off <<= 1) {
    s  += __shfl_xor(s, off);
    sq += __shfl_xor(sq, off);
  }
  if (CS > 1) {
    if (lane < W) { redS[wave * W + lane] = s; redQ[wave * W + lane] = sq; }
    __syncthreads();
    s = 0.f; sq = 0.f;
#pragma unroll
    for (int w2 = 0; w2 < CS; ++w2) { s += redS[w2 * W + v]; sq += redQ[w2 * W + v]; }
  }
  const float mean = s / (float)COUT;
  const float var  = sq / (float)COUT - mean * mean;
  const float rstd = rsqrtf(var + EPS);

  // ---- normalize + leaky + mask + store (coalesced W-segments) ----
  const uint8_t* morow = mout + (((size_t)b * W + zo) * W + yo) * W;
  const float mk = morow[v] ? 1.f : 0.f;
#pragma unroll
  for (int j = 0; j < CPG; ++j) {
    const int cc = g * CPG + j;
    float r = (ys[cc * WP + v] - mean) * rstd;
    r = r * gamma[cc] + beta[cc];
    r = r > 0.f ? r : SLOPE * r;
    r *= mk;
    out[(((size_t)(b * COUT + cc) * W + zo) * W + yo) * W + v] = r;
  }
}

// t4: [2][512][512] -> out[2][512]
__global__ void reduce_max_k(const float* __restrict__ t4,
                             float* __restrict__ out) {
  const int pair = blockIdx.x;          // b*512 + c
  const int lane = threadIdx.x;         // 64
  const float* p = t4 + (size_t)pair * 512;
  float m = -1e30f;
  for (int i = lane; i < 512; i += 64) m = fmaxf(m, p[i]);
  for (int off = 32; off; off >>= 1) m = fmaxf(m, __shfl_xor(m, off));
  if (lane == 0) out[pair] = m;
}

// ---------------------------------------------------------------------------
extern "C" void kernel_launch(void* const* d_in, const int* in_sizes, int n_in,
                              void* d_out, int out_size, void* d_ws, size_t ws_size,
                              hipStream_t stream) {
  const float*   x    = (const float*)d_in[0];
  const uint8_t* mraw = (const uint8_t*)d_in[1];
  const float* w1 = (const float*)d_in[2];
  const float* g1 = (const float*)d_in[3];
  const float* b1 = (const float*)d_in[4];
  const float* w2 = (const float*)d_in[5];
  const float* g2 = (const float*)d_in[6];
  const float* b2 = (const float*)d_in[7];
  const float* w3 = (const float*)d_in[8];
  const float* g3 = (const float*)d_in[9];
  const float* b3 = (const float*)d_in[10];
  const float* w4 = (const float*)d_in[11];
  const float* g4 = (const float*)d_in[12];
  const float* b4 = (const float*)d_in[13];
  float* out = (float*)d_out;
  char*  ws  = (char*)d_ws;

  // ---- workspace layout (bytes). t3/wt4/t4 alias t1's region (dead after
  // block2): t3@[0,8.39MB), wt4@[16MB,30.94MB), t4@[32MB,34.1MB). ----
  const size_t T1o  = 0;                         // 134,217,728 B
  const size_t T3o  = 0;                         //   8,388,608 B (alias)
  const size_t WT4o = (size_t)16 * 1024 * 1024;  //  14,155,776 B (alias)
  const size_t T4o  = (size_t)32 * 1024 * 1024;  //   2,097,152 B (alias)
  const size_t T2o  = 134217728;                 //  33,554,432 B
  const size_t WT1o = T2o + 33554432;            //      20,736 B
  const size_t WT2o = WT1o + 20992;              //     884,736 B
  const size_t WT3o = WT2o + 884736;             //   3,538,944 B
  const size_t M1o  = WT3o + 3538944;            //     524,288 B
  const size_t M2o  = M1o + 524288;              //      65,536 B
  const size_t M3o  = M2o + 65536;               //       8,192 B
  const size_t M4o  = M3o + 8192;                //       1,024 B
  const size_t FLo  = M4o + 1024;                //           4 B

  float*   t1  = (float*)(ws + T1o);
  float*   t2  = (float*)(ws + T2o);
  float*   t3  = (float*)(ws + T3o);
  float*   t4  = (float*)(ws + T4o);
  float*   wt1 = (float*)(ws + WT1o);
  float*   wt2 = (float*)(ws + WT2o);
  float*   wt3 = (float*)(ws + WT3o);
  float*   wt4 = (float*)(ws + WT4o);
  uint8_t* m1  = (uint8_t*)(ws + M1o);
  uint8_t* m2  = (uint8_t*)(ws + M2o);
  uint8_t* m3  = (uint8_t*)(ws + M3o);
  uint8_t* m4  = (uint8_t*)(ws + M4o);
  unsigned* flag = (unsigned*)(ws + FLo);

  const int NM1 = 2 * 64 * 64 * 64;  // 524288 mask elements

  hipMemsetAsync(flag, 0, 4, stream);
  mask_detect_k<<<256, 256, 0, stream>>>(mraw, NM1, flag);
  mask_convert_k<<<(NM1 + 255) / 256, 256, 0, stream>>>(mraw, flag, m1, NM1);
  mask_down_k<<<(2 * 32 * 32 * 32 + 255) / 256, 256, 0, stream>>>(m1, m2, 64);
  mask_down_k<<<(2 * 16 * 16 * 16 + 255) / 256, 256, 0, stream>>>(m2, m3, 32);
  mask_down_k<<<(2 * 8 * 8 * 8 + 255) / 256, 256, 0, stream>>>(m3, m4, 16);

  wtrans_k<<<(64 * 81 + 255) / 256, 256, 0, stream>>>(w1, wt1, 64, 81);
  wtrans_k<<<(128 * 1728 + 255) / 256, 256, 0, stream>>>(w2, wt2, 128, 1728);
  wtrans_k<<<(256 * 3456 + 255) / 256, 256, 0, stream>>>(w3, wt3, 256, 3456);

  // block1: 3->64, stride 1, input masked by m1, output masked by m1
  conv_block<3, 64, 64, 1, true><<<2 * 64 * 64, 64, 0, stream>>>(
      x, wt1, g1, b1, m1, m1, t1);
  // block2: 64->128, stride 2, mask m2
  conv_block<64, 128, 64, 2, false><<<2 * 32 * 32, 128, 0, stream>>>(
      t1, wt2, g2, b2, nullptr, m2, t2);
  // wt4 transpose into t1's (now dead) region
  wtrans_k<<<(512 * 6912 + 255) / 256, 256, 0, stream>>>(w4, wt4, 512, 6912);
  // block3: 128->256, stride 2, mask m3
  conv_block<128, 256, 32, 2, false><<<2 * 16 * 16, 256, 0, stream>>>(
      t2, wt3, g3, b3, nullptr, m3, t3);
  // block4: 256->512, stride 2, mask m4
  conv_block<256, 512, 16, 2, false><<<2 * 8 * 8, 512, 0, stream>>>(
      t3, wt4, g4, b4, nullptr, m4, t4);

  reduce_max_k<<<2 * 512, 64, 0, stream>>>(t4, out);

  (void)in_sizes; (void)n_in; (void)out_size; (void)ws_size;
}

// Round 2
// 475.534 us; speedup vs baseline: 4.6416x; 4.6416x over previous
//
#include <hip/hip_runtime.h>
#include <hip/hip_bf16.h>
#include <stdint.h>

#define EPS 1e-5f
#define SLOPE 0.2f

typedef __attribute__((ext_vector_type(8))) short short8;
typedef __attribute__((ext_vector_type(4))) float f32x4;

static __device__ inline ushort f2bf(float f) {
  __hip_bfloat16 h = __float2bfloat16(f);
  return *reinterpret_cast<ushort*>(&h);
}

// ---------------------------------------------------------------------------
// Mask dtype detection (bool vs 4-byte layout) — same as round 0.
// ---------------------------------------------------------------------------
__global__ void mask_detect_k(const uint8_t* __restrict__ raw, int nbytes,
                              unsigned* __restrict__ flag) {
  unsigned local = 0;
  for (int i = blockIdx.x * blockDim.x + threadIdx.x; i < nbytes;
       i += gridDim.x * blockDim.x)
    if (i & 3) local |= raw[i];
  if (local) atomicOr(flag, 1u);
}

__global__ void mask_convert_k(const uint8_t* __restrict__ raw,
                               const unsigned* __restrict__ flag,
                               uint8_t* __restrict__ m1, int n) {
  int i = blockIdx.x * blockDim.x + threadIdx.x;
  if (i >= n) return;
  uint8_t v;
  if (*flag) {
    v = raw[i];
  } else {
    size_t j = 4 * (size_t)i;
    v = (uint8_t)(raw[j] | raw[j + 1] | raw[j + 2] | raw[j + 3]);
  }
  m1[i] = v ? 1 : 0;
}

__global__ void mask_down_k(const uint8_t* __restrict__ mi,
                            uint8_t* __restrict__ mo, int DIN) {
  int W = DIN >> 1;
  int id = blockIdx.x * blockDim.x + threadIdx.x;
  int total = 2 * W * W * W;
  if (id >= total) return;
  int xo = id % W; int t = id / W;
  int yo = t % W;  t /= W;
  int zo = t % W;  int b = t / W;
  int any = 0;
  for (int dz = 0; dz < 3; ++dz) {
    int z = 2 * zo + dz - 1; if (z < 0 || z >= DIN) continue;
    for (int dy = 0; dy < 3; ++dy) {
      int y = 2 * yo + dy - 1; if (y < 0 || y >= DIN) continue;
      for (int dx = 0; dx < 3; ++dx) {
        int x = 2 * xo + dx - 1; if (x < 0 || x >= DIN) continue;
        any |= mi[(((size_t)b * DIN + z) * DIN + y) * DIN + x];
      }
    }
  }
  mo[id] = any ? 1 : 0;
}

// block1 weight transpose: w[64][81] -> wt[81][64] fp32
__global__ void wtrans_k(const float* __restrict__ w, float* __restrict__ wt,
                         int COUT, int K) {
  int id = blockIdx.x * blockDim.x + threadIdx.x;
  if (id >= COUT * K) return;
  int c = id % COUT;
  int k = id / COUT;
  wt[id] = w[(size_t)c * K + k];
}

// GEMM weights: w[c][ci*27+off] f32 -> wb[c][off*CIN+ci] bf16
__global__ void wbf_k(const float* __restrict__ w, ushort* __restrict__ wb,
                      int COUT, int CIN) {
  int K = CIN * 27;
  int id = blockIdx.x * blockDim.x + threadIdx.x;
  if (id >= COUT * K) return;
  int kn = id % K;
  int c  = id / K;
  int off = kn / CIN;
  int ci  = kn % CIN;
  wb[(size_t)c * K + kn] = f2bf(w[(size_t)c * K + ci * 27 + off]);
}

// ---------------------------------------------------------------------------
// Block1: fp32 row-conv (3->64, stride 1) + LN + leaky + mask, output
// channels-last bf16 [vox][64].
// ---------------------------------------------------------------------------
template <int CIN, int COUT, int DIN>
__global__ __launch_bounds__(COUT) void conv1_block(
    const float* __restrict__ in,        // [2][CIN][DIN][DIN][DIN]
    const float* __restrict__ wt,        // [CIN*27][COUT]
    const float* __restrict__ gamma,
    const float* __restrict__ beta,
    const uint8_t* __restrict__ msk,     // [2][DIN^3]
    ushort* __restrict__ out)            // [2*DIN^3][COUT] bf16 channels-last
{
  constexpr int W  = DIN;
  constexpr int WP = W + 1;
  const int c = threadIdx.x;             // 64 threads, 1 wave

  int bid = blockIdx.x;
  const int yo = bid % W; bid /= W;
  const int zo = bid % W; bid /= W;
  const int b  = bid;

  float acc[W];
#pragma unroll
  for (int v = 0; v < W; ++v) acc[v] = 0.f;

  for (int dz = 0; dz < 3; ++dz) {
    const int zin = zo + dz - 1;
    if (zin < 0 || zin >= DIN) continue;
    for (int dy = 0; dy < 3; ++dy) {
      const int yin = yo + dy - 1;
      if (yin < 0 || yin >= DIN) continue;
      const uint8_t* mrow = msk + ((size_t)b * DIN + zin) * DIN * DIN + (size_t)yin * DIN;
      for (int ci = 0; ci < CIN; ++ci) {
        const float* rp = in + (((size_t)(b * CIN + ci) * DIN + zin) * DIN + yin) * DIN;
        float xr[DIN + 2];
        xr[0] = 0.f; xr[DIN + 1] = 0.f;
#pragma unroll
        for (int i = 0; i < DIN; ++i) {
          float xv = rp[i];
          xr[i + 1] = mrow[i] ? xv : 0.f;
        }
        const float* wp = wt + (size_t)(((ci * 3 + dz) * 3 + dy) * 3) * COUT + c;
        const float w0 = wp[0];
        const float w1 = wp[COUT];
        const float w2 = wp[2 * COUT];
#pragma unroll
        for (int v = 0; v < W; ++v) {
          acc[v] += xr[v + 0] * w0;
          acc[v] += xr[v + 1] * w1;
          acc[v] += xr[v + 2] * w2;
        }
      }
    }
  }

  __shared__ float ys[COUT * WP];
#pragma unroll
  for (int v = 0; v < W; ++v) ys[c * WP + v] = acc[v];
  __syncthreads();

  // per-thread voxel v = threadIdx.x (64 voxels in this row, 64 channels each)
  const int v = threadIdx.x;
  float s = 0.f, sq = 0.f;
#pragma unroll
  for (int cc = 0; cc < COUT; ++cc) {
    float val = ys[cc * WP + v];
    s += val; sq += val * val;
  }
  const float mean = s / (float)COUT;
  const float var  = sq / (float)COUT - mean * mean;
  const float rstd = rsqrtf(var + EPS);

  const uint8_t* morow = msk + (((size_t)b * W + zo) * W + yo) * W;
  const float mk = morow[v] ? 1.f : 0.f;

  ushort* op = out + ((((size_t)b * W + zo) * W + yo) * W + v) * (size_t)COUT;
#pragma unroll
  for (int j0 = 0; j0 < COUT; j0 += 8) {
    uint4 u;
    uint* pu = (uint*)&u;
#pragma unroll
    for (int p = 0; p < 4; ++p) {
      int cc0 = j0 + 2 * p;
      float r0 = (ys[cc0 * WP + v] - mean) * rstd * gamma[cc0] + beta[cc0];
      float r1 = (ys[(cc0 + 1) * WP + v] - mean) * rstd * gamma[cc0 + 1] + beta[cc0 + 1];
      r0 = (r0 > 0.f ? r0 : SLOPE * r0) * mk;
      r1 = (r1 > 0.f ? r1 : SLOPE * r1) * mk;
      pu[p] = ((uint)f2bf(r1) << 16) | (uint)f2bf(r0);
    }
    *reinterpret_cast<uint4*>(op + j0) = u;
  }
}

// ---------------------------------------------------------------------------
// Implicit-GEMM conv (3x3x3, pad 1, stride S): C[m=cout][n=vox] = sum_k A*B
// A = weights [COUT][K] bf16 (k = off*CIN+ci), B = im2col gathered from
// channels-last input [2][DIN][DIN][DIN][CIN] bf16. 128x128 tile, BK=64,
// 4 waves of 64x64, double-buffered XOR-swizzled LDS. Raw f32 out
// channels-last [vox][COUT].
// ---------------------------------------------------------------------------
template <int CIN, int COUT, int DIN, int S, int L2CIN>
__global__ __launch_bounds__(256) void conv_gemm(
    const ushort* __restrict__ in,
    const ushort* __restrict__ wbf,
    float* __restrict__ rawout,
    const ushort* __restrict__ zpage)
{
  constexpr int W  = DIN / S;
  constexpr int K  = 27 * CIN;
  constexpr int NT = K / 64;                      // k-steps
  constexpr int LW = (W == 32) ? 5 : (W == 16) ? 4 : 3;

  const int t    = threadIdx.x;
  const int lane = t & 63;
  const int wave = t >> 6;
  const int n0   = blockIdx.x * 128;
  const int m0   = blockIdx.y * 128;

  __shared__ short As[2][128 * 64];
  __shared__ short Bs[2][128 * 64];

  // per-task (j=0..3) invariants
  int zb[4], yb[4], xb[4], kc8[4], swz[4];
  size_t bb[4];
  const ushort* aptr[4];
#pragma unroll
  for (int j = 0; j < 4; ++j) {
    int q  = t + 256 * j;
    int nl = q >> 3, kc = q & 7;
    kc8[j] = kc * 8;
    swz[j] = nl * 64 + (((kc ^ (nl & 7)) << 3));
    int ng = n0 + nl;
    int xo = ng & (W - 1), yo = (ng >> LW) & (W - 1),
        zo = (ng >> (2 * LW)) & (W - 1), b = ng >> (3 * LW);
    xb[j] = xo * S; yb[j] = yo * S; zb[j] = zo * S;
    bb[j] = (size_t)b * CIN * DIN * DIN * DIN;
    aptr[j] = wbf + (size_t)(m0 + nl) * K + kc * 8;
  }

  short8 ar[4], br[4];

  auto LOADK = [&](int kb) {
    const int off = (kb * 64) >> L2CIN;
    const int ci0 = (kb * 64) & (CIN - 1);
    const int dz = off / 9, rr = off % 9;
    const int dy = rr / 3, dx = rr % 3;
#pragma unroll
    for (int j = 0; j < 4; ++j) {
      ar[j] = *reinterpret_cast<const short8*>(aptr[j] + kb * 64);
      int zin = zb[j] + dz - 1;
      int yin = yb[j] + dy - 1;
      int xin = xb[j] + dx - 1;
      bool ok = ((unsigned)zin < (unsigned)DIN) &&
                ((unsigned)yin < (unsigned)DIN) &&
                ((unsigned)xin < (unsigned)DIN);
      const ushort* p = ok
          ? in + bb[j] + (((size_t)zin * DIN + yin) * DIN + xin) * CIN + ci0 + kc8[j]
          : zpage;
      br[j] = *reinterpret_cast<const short8*>(p);
    }
  };

  auto WRITEK = [&](int buf) {
#pragma unroll
    for (int j = 0; j < 4; ++j) {
      *reinterpret_cast<short8*>(&As[buf][swz[j]]) = ar[j];
      *reinterpret_cast<short8*>(&Bs[buf][swz[j]]) = br[j];
    }
  };

  f32x4 acc[4][4];
#pragma unroll
  for (int i = 0; i < 4; ++i)
#pragma unroll
    for (int j = 0; j < 4; ++j) acc[i][j] = (f32x4)(0.f);

  const int wm = (wave & 1) * 64;
  const int wn = (wave >> 1) * 64;

  LOADK(0);
  for (int kb = 0; kb < NT; ++kb) {
    const int buf = kb & 1;
    WRITEK(buf);
    if (kb + 1 < NT) LOADK(kb + 1);
    __syncthreads();

    short8 afr[4][2], bfr[4][2];
#pragma unroll
    for (int mf = 0; mf < 4; ++mf)
#pragma unroll
      for (int kh = 0; kh < 2; ++kh) {
        int row  = wm + mf * 16 + (lane & 15);
        int slot = (lane >> 4) + kh * 4;
        afr[mf][kh] = *reinterpret_cast<const short8*>(
            &As[buf][row * 64 + ((slot ^ (row & 7)) << 3)]);
      }
#pragma unroll
    for (int nf = 0; nf < 4; ++nf)
#pragma unroll
      for (int kh = 0; kh < 2; ++kh) {
        int row  = wn + nf * 16 + (lane & 15);
        int slot = (lane >> 4) + kh * 4;
        bfr[nf][kh] = *reinterpret_cast<const short8*>(
            &Bs[buf][row * 64 + ((slot ^ (row & 7)) << 3)]);
      }
#pragma unroll
    for (int mf = 0; mf < 4; ++mf)
#pragma unroll
      for (int nf = 0; nf < 4; ++nf)
#pragma unroll
        for (int kh = 0; kh < 2; ++kh)
          acc[mf][nf] = __builtin_amdgcn_mfma_f32_16x16x32_bf16(
              afr[mf][kh], bfr[nf][kh], acc[mf][nf], 0, 0, 0);
  }

  // epilogue: C row=m (lane>>4)*4+r, col=n (lane&15); channels-last store
#pragma unroll
  for (int mf = 0; mf < 4; ++mf)
#pragma unroll
    for (int nf = 0; nf < 4; ++nf) {
      int mg = m0 + wm + mf * 16 + ((lane >> 4) << 2);
      int ng = n0 + wn + nf * 16 + (lane & 15);
      *reinterpret_cast<f32x4*>(&rawout[(size_t)ng * COUT + mg]) = acc[mf][nf];
    }
}

// ---------------------------------------------------------------------------
// Fused LayerNorm(channel) + LeakyReLU + mask on channels-last raw f32.
// One wave per voxel. BF16OUT: write bf16 (next layer input) else f32.
// ---------------------------------------------------------------------------
template <int C, bool BF16OUT>
__global__ __launch_bounds__(256) void ln_mask_k(
    const float* __restrict__ raw,       // [nvox][C]
    const float* __restrict__ gamma,
    const float* __restrict__ beta,
    const uint8_t* __restrict__ msk,     // [nvox]
    void* __restrict__ outv, int nvox)
{
  constexpr int E = C / 64;
  const int lane = threadIdx.x & 63;
  const int vox  = blockIdx.x * 4 + (threadIdx.x >> 6);
  if (vox >= nvox) return;

  const float* p = raw + (size_t)vox * C;
  float v[E];
  float s = 0.f, sq = 0.f;
#pragma unroll
  for (int e = 0; e < E; ++e) {
    v[e] = p[e * 64 + lane];
    s += v[e]; sq += v[e] * v[e];
  }
#pragma unroll
  for (int off = 32; off; off >>= 1) {
    s  += __shfl_xor(s, off);
    sq += __shfl_xor(sq, off);
  }
  const float mean = s / (float)C;
  const float var  = sq / (float)C - mean * mean;
  const float rstd = rsqrtf(var + EPS);
  const float mk   = msk[vox] ? 1.f : 0.f;

#pragma unroll
  for (int e = 0; e < E; ++e) {
    int c = e * 64 + lane;
    float r = (v[e] - mean) * rstd * gamma[c] + beta[c];
    r = (r > 0.f ? r : SLOPE * r) * mk;
    if (BF16OUT)
      ((ushort*)outv)[(size_t)vox * C + c] = f2bf(r);
    else
      ((float*)outv)[(size_t)vox * C + c] = r;
  }
}

// t4 [2*512 vox][512 c] f32 -> partial max over 64-voxel groups
__global__ void rmax1_k(const float* __restrict__ t4, float* __restrict__ pm) {
  const int g = blockIdx.x;   // 0..7
  const int b = blockIdx.y;   // 0..1
  const int c = threadIdx.x;  // 0..511
  float m = -1e30f;
  for (int v = g * 64; v < g * 64 + 64; ++v)
    m = fmaxf(m, t4[((size_t)(b * 512 + v)) * 512 + c]);
  pm[((size_t)b * 8 + g) * 512 + c] = m;
}

__global__ void rmax2_k(const float* __restrict__ pm, float* __restrict__ out) {
  const int b = blockIdx.x;
  const int c = threadIdx.x;
  float m = -1e30f;
  for (int g = 0; g < 8; ++g) m = fmaxf(m, pm[((size_t)b * 8 + g) * 512 + c]);
  out[b * 512 + c] = m;
}

// ---------------------------------------------------------------------------
extern "C" void kernel_launch(void* const* d_in, const int* in_sizes, int n_in,
                              void* d_out, int out_size, void* d_ws, size_t ws_size,
                              hipStream_t stream) {
  const float*   x    = (const float*)d_in[0];
  const uint8_t* mraw = (const uint8_t*)d_in[1];
  const float* w1 = (const float*)d_in[2];
  const float* g1 = (const float*)d_in[3];
  const float* b1 = (const float*)d_in[4];
  const float* w2 = (const float*)d_in[5];
  const float* g2 = (const float*)d_in[6];
  const float* b2 = (const float*)d_in[7];
  const float* w3 = (const float*)d_in[8];
  const float* g3 = (const float*)d_in[9];
  const float* b3 = (const float*)d_in[10];
  const float* w4 = (const float*)d_in[11];
  const float* g4 = (const float*)d_in[12];
  const float* b4 = (const float*)d_in[13];
  float* out = (float*)d_out;
  char*  ws  = (char*)d_ws;

  // ---- workspace layout (bytes) ----
  const size_t ZP  = 0;                      // flag @0, zero-page @16 (64 B)
  const size_t T1  = 256;                    // 67,108,864  bf16 CL [524288][64]
  const size_t R2  = 67109120;               // 33,554,432  f32 [65536][128]
  const size_t T2  = 100663552;              // 16,777,216  bf16 [65536][128]
  const size_t R3  = 117440768;              //  8,388,608  f32 [8192][256]
  const size_t T3  = 125829376;              //  4,194,304  bf16 [8192][256]
  const size_t R4  = 130023680;              //  2,097,152  f32 [1024][512]
  const size_t T4  = 132120832;              //  2,097,152  f32 [1024][512]
  const size_t PM  = 134217984;              //     32,768
  const size_t WT1 = 134250752;              //     20,992
  const size_t WB2 = 134271744;              //    442,368
  const size_t WB3 = 134714112;              //  1,769,472
  const size_t WB4 = 136483584;              //  7,077,888
  const size_t M1  = 143561472;              //    524,288
  const size_t M2  = 144085760;              //     65,536
  const size_t M3  = 144151296;              //      8,192
  const size_t M4  = 144159488;              //      1,024

  unsigned* flag = (unsigned*)(ws + ZP);
  const ushort* zpage = (const ushort*)(ws + ZP + 16);
  ushort* t1  = (ushort*)(ws + T1);
  float*  r2  = (float*)(ws + R2);
  ushort* t2  = (ushort*)(ws + T2);
  float*  r3  = (float*)(ws + R3);
  ushort* t3  = (ushort*)(ws + T3);
  float*  r4  = (float*)(ws + R4);
  float*  t4  = (float*)(ws + T4);
  float*  pm  = (float*)(ws + PM);
  float*  wt1 = (float*)(ws + WT1);
  ushort* wb2 = (ushort*)(ws + WB2);
  ushort* wb3 = (ushort*)(ws + WB3);
  ushort* wb4 = (ushort*)(ws + WB4);
  uint8_t* m1 = (uint8_t*)(ws + M1);
  uint8_t* m2 = (uint8_t*)(ws + M2);
  uint8_t* m3 = (uint8_t*)(ws + M3);
  uint8_t* m4 = (uint8_t*)(ws + M4);

  const int NM1 = 2 * 64 * 64 * 64;

  hipMemsetAsync(ws + ZP, 0, 64, stream);
  mask_detect_k<<<256, 256, 0, stream>>>(mraw, NM1, flag);
  mask_convert_k<<<(NM1 + 255) / 256, 256, 0, stream>>>(mraw, flag, m1, NM1);
  mask_down_k<<<(2 * 32 * 32 * 32 + 255) / 256, 256, 0, stream>>>(m1, m2, 64);
  mask_down_k<<<(2 * 16 * 16 * 16 + 255) / 256, 256, 0, stream>>>(m2, m3, 32);
  mask_down_k<<<(2 * 8 * 8 * 8 + 255) / 256, 256, 0, stream>>>(m3, m4, 16);

  wtrans_k<<<(64 * 81 + 255) / 256, 256, 0, stream>>>(w1, wt1, 64, 81);
  wbf_k<<<(128 * 1728 + 255) / 256, 256, 0, stream>>>(w2, wb2, 128, 64);
  wbf_k<<<(256 * 3456 + 255) / 256, 256, 0, stream>>>(w3, wb3, 256, 128);
  wbf_k<<<(512 * 6912 + 255) / 256, 256, 0, stream>>>(w4, wb4, 512, 256);

  // block1: fp32 conv + LN + mask -> bf16 channels-last
  conv1_block<3, 64, 64><<<2 * 64 * 64, 64, 0, stream>>>(x, wt1, g1, b1, m1, t1);

  // block2: 64->128, s2
  conv_gemm<64, 128, 64, 2, 6><<<dim3(512, 1), 256, 0, stream>>>(t1, wb2, r2, zpage);
  ln_mask_k<128, true><<<65536 / 4, 256, 0, stream>>>(r2, g2, b2, m2, t2, 65536);

  // block3: 128->256, s2
  conv_gemm<128, 256, 32, 2, 7><<<dim3(64, 2), 256, 0, stream>>>(t2, wb3, r3, zpage);
  ln_mask_k<256, true><<<8192 / 4, 256, 0, stream>>>(r3, g3, b3, m3, t3, 8192);

  // block4: 256->512, s2
  conv_gemm<256, 512, 16, 2, 8><<<dim3(8, 4), 256, 0, stream>>>(t3, wb4, r4, zpage);
  ln_mask_k<512, false><<<1024 / 4, 256, 0, stream>>>(r4, g4, b4, m4, t4, 1024);

  rmax1_k<<<dim3(8, 2), 512, 0, stream>>>(t4, pm);
  rmax2_k<<<2, 512, 0, stream>>>(pm, out);

  (void)in_sizes; (void)n_in; (void)out_size; (void)ws_size;
}

// Round 3
// 221.278 us; speedup vs baseline: 9.9750x; 2.1490x over previous
//
#include <hip/hip_runtime.h>
#include <hip/hip_bf16.h>
#include <stdint.h>

#define EPS 1e-5f
#define SLOPE 0.2f

typedef __attribute__((ext_vector_type(8))) short short8;
typedef __attribute__((ext_vector_type(4))) float f32x4;

static __device__ inline ushort f2bf(float f) {
  __hip_bfloat16 h = __float2bfloat16(f);
  return *reinterpret_cast<ushort*>(&h);
}

static __device__ inline short8 u4_to_s8(uint a, uint b, uint c, uint d) {
  union { uint4 u; short8 s; } cv;
  cv.u.x = a; cv.u.y = b; cv.u.z = c; cv.u.w = d;
  return cv.s;
}

// ---------------------------------------------------------------------------
// Mask dtype detection (bool vs 4-byte layout).
// ---------------------------------------------------------------------------
__global__ void mask_detect_k(const uint8_t* __restrict__ raw, int nbytes,
                              unsigned* __restrict__ flag) {
  unsigned local = 0;
  for (int i = blockIdx.x * blockDim.x + threadIdx.x; i < nbytes;
       i += gridDim.x * blockDim.x)
    if (i & 3) local |= raw[i];
  if (local) atomicOr(flag, 1u);
}

__global__ void mask_convert_k(const uint8_t* __restrict__ raw,
                               const unsigned* __restrict__ flag,
                               uint8_t* __restrict__ m1, int n) {
  int i = blockIdx.x * blockDim.x + threadIdx.x;
  if (i >= n) return;
  uint8_t v;
  if (*flag) {
    v = raw[i];
  } else {
    size_t j = 4 * (size_t)i;
    v = (uint8_t)(raw[j] | raw[j + 1] | raw[j + 2] | raw[j + 3]);
  }
  m1[i] = v ? 1 : 0;
}

__global__ void mask_down_k(const uint8_t* __restrict__ mi,
                            uint8_t* __restrict__ mo, int DIN) {
  int W = DIN >> 1;
  int id = blockIdx.x * blockDim.x + threadIdx.x;
  int total = 2 * W * W * W;
  if (id >= total) return;
  int xo = id % W; int t = id / W;
  int yo = t % W;  t /= W;
  int zo = t % W;  int b = t / W;
  int any = 0;
  for (int dz = 0; dz < 3; ++dz) {
    int z = 2 * zo + dz - 1; if (z < 0 || z >= DIN) continue;
    for (int dy = 0; dy < 3; ++dy) {
      int y = 2 * yo + dy - 1; if (y < 0 || y >= DIN) continue;
      for (int dx = 0; dx < 3; ++dx) {
        int x = 2 * xo + dx - 1; if (x < 0 || x >= DIN) continue;
        any |= mi[(((size_t)b * DIN + z) * DIN + y) * DIN + x];
      }
    }
  }
  mo[id] = any ? 1 : 0;
}

// GEMM weights for blocks 2-4: w[c][ci*27+off] f32 -> wb[c][off*CIN+ci] bf16
__global__ void wbf_k(const float* __restrict__ w, ushort* __restrict__ wb,
                      int COUT, int CIN) {
  int K = CIN * 27;
  int id = blockIdx.x * blockDim.x + threadIdx.x;
  if (id >= COUT * K) return;
  int kn = id % K;
  int c  = id / K;
  int off = kn / CIN;
  int ci  = kn % CIN;
  wb[(size_t)c * K + kn] = f2bf(w[(size_t)c * K + ci * 27 + off]);
}

// Block1 weights: w1[64][3][27] -> wb1[64][128] bf16, k = tap*4+ci (padded)
__global__ void wb1_k(const float* __restrict__ w, ushort* __restrict__ wb) {
  int id = blockIdx.x * blockDim.x + threadIdx.x;
  if (id >= 64 * 128) return;
  int k = id & 127;
  int c = id >> 7;
  int tap = k >> 2, ci = k & 3;
  float v = (tap < 27 && ci < 3) ? w[c * 81 + ci * 27 + tap] : 0.f;
  wb[id] = f2bf(v);
}

// Pre-pass: x [2][3][64^3] f32 + mask -> xcl [2*64^3][4] bf16 (masked, ci3=0)
__global__ void xcl_k(const float* __restrict__ x, const uint8_t* __restrict__ m1,
                      ushort* __restrict__ xcl) {
  int id = blockIdx.x * blockDim.x + threadIdx.x;
  if (id >= 2 * 262144) return;
  int b  = id >> 18;
  int sp = id & 262143;
  float mk = m1[id] ? 1.f : 0.f;
  size_t base = (size_t)b * 3 * 262144 + sp;
  float x0 = x[base] * mk;
  float x1 = x[base + 262144] * mk;
  float x2 = x[base + 2 * 262144] * mk;
  uint2 u;
  u.x = ((uint)f2bf(x1) << 16) | (uint)f2bf(x0);
  u.y = (uint)f2bf(x2);
  *reinterpret_cast<uint2*>(xcl + (size_t)id * 4) = u;
}

// ---------------------------------------------------------------------------
// Block1 implicit GEMM: M=64 (cout), N=524288 (vox), K=128 (32 taps x 4 ci,
// taps>=27 and ci=3 are zero-padded). BM=64, BN=128, BK=64, 4 waves of
// 64x32. Epilogue fuses LayerNorm(64ch)+leaky+mask, writes bf16 CL [vox][64].
// ---------------------------------------------------------------------------
__global__ __launch_bounds__(256) void conv1_gemm(
    const ushort* __restrict__ xcl,     // [2*64^3][4] bf16
    const ushort* __restrict__ wb1,     // [64][128] bf16
    const float* __restrict__ gamma,
    const float* __restrict__ beta,
    const uint8_t* __restrict__ msk,    // [2*64^3]
    ushort* __restrict__ out)           // [2*64^3][64] bf16
{
  const int t    = threadIdx.x;
  const int lane = t & 63;
  const int wave = t >> 6;
  const int n0   = blockIdx.x * 128;
  const int wn   = wave * 32;

  __shared__ short As[2][64 * 64];
  __shared__ short Bs[2][128 * 64];

  // B tasks: 128 rows x 8 kc -> j=0..3 ; A tasks: 64 rows x 8 kc -> j=0..1
  int bz[4], by[4], bx[4], bkc[4], bswz[4], bb[4];
  int aswz[2];
  const ushort* aptr[2];
#pragma unroll
  for (int j = 0; j < 4; ++j) {
    int q  = t + 256 * j;
    int nl = q >> 3, kc = q & 7;
    bkc[j] = kc;
    bswz[j] = nl * 64 + ((kc ^ (nl & 7)) << 3);
    int ng = n0 + nl;
    bx[j] = ng & 63; by[j] = (ng >> 6) & 63; bz[j] = (ng >> 12) & 63;
    bb[j] = ng >> 18;
  }
#pragma unroll
  for (int j = 0; j < 2; ++j) {
    int q  = t + 256 * j;
    int ml = q >> 3, kc = q & 7;
    aswz[j] = ml * 64 + ((kc ^ (ml & 7)) << 3);
    aptr[j] = wb1 + ml * 128 + kc * 8;
  }

  short8 ar[2], br[4];

  auto LOADK = [&](int kb) {
#pragma unroll
    for (int j = 0; j < 2; ++j)
      ar[j] = *reinterpret_cast<const short8*>(aptr[j] + kb * 64);
#pragma unroll
    for (int j = 0; j < 4; ++j) {
      uint w0 = 0, w1 = 0, w2 = 0, w3 = 0;
      int tp0 = kb * 16 + bkc[j] * 2;
#pragma unroll
      for (int h = 0; h < 2; ++h) {
        int tp = tp0 + h;
        uint lo = 0, hi = 0;
        if (tp < 27) {
          int dz = tp / 9, rr = tp % 9;
          int dy = rr / 3, dx = rr % 3;
          int zin = bz[j] + dz - 1;
          int yin = by[j] + dy - 1;
          int xin = bx[j] + dx - 1;
          if ((unsigned)zin < 64u && (unsigned)yin < 64u && (unsigned)xin < 64u) {
            size_t idx = (((size_t)(bb[j] * 64 + zin) * 64 + yin) * 64 + xin);
            uint2 v = *reinterpret_cast<const uint2*>(xcl + idx * 4);
            lo = v.x; hi = v.y;
          }
        }
        if (h == 0) { w0 = lo; w1 = hi; } else { w2 = lo; w3 = hi; }
      }
      br[j] = u4_to_s8(w0, w1, w2, w3);
    }
  };

  auto WRITEK = [&](int buf) {
#pragma unroll
    for (int j = 0; j < 2; ++j)
      *reinterpret_cast<short8*>(&As[buf][aswz[j]]) = ar[j];
#pragma unroll
    for (int j = 0; j < 4; ++j)
      *reinterpret_cast<short8*>(&Bs[buf][bswz[j]]) = br[j];
  };

  f32x4 acc[4][2];
#pragma unroll
  for (int i = 0; i < 4; ++i)
#pragma unroll
    for (int j = 0; j < 2; ++j) acc[i][j] = (f32x4)(0.f);

  auto COMPUTE = [&](int buf) {
    short8 afr[4][2], bfr[2][2];
#pragma unroll
    for (int mf = 0; mf < 4; ++mf)
#pragma unroll
      for (int kh = 0; kh < 2; ++kh) {
        int row  = mf * 16 + (lane & 15);
        int slot = (lane >> 4) + kh * 4;
        afr[mf][kh] = *reinterpret_cast<const short8*>(
            &As[buf][row * 64 + ((slot ^ (row & 7)) << 3)]);
      }
#pragma unroll
    for (int nf = 0; nf < 2; ++nf)
#pragma unroll
      for (int kh = 0; kh < 2; ++kh) {
        int row  = wn + nf * 16 + (lane & 15);
        int slot = (lane >> 4) + kh * 4;
        bfr[nf][kh] = *reinterpret_cast<const short8*>(
            &Bs[buf][row * 64 + ((slot ^ (row & 7)) << 3)]);
      }
#pragma unroll
    for (int mf = 0; mf < 4; ++mf)
#pragma unroll
      for (int nf = 0; nf < 2; ++nf)
#pragma unroll
        for (int kh = 0; kh < 2; ++kh)
          acc[mf][nf] = __builtin_amdgcn_mfma_f32_16x16x32_bf16(
              afr[mf][kh], bfr[nf][kh], acc[mf][nf], 0, 0, 0);
  };

  LOADK(0);
  WRITEK(0);
  LOADK(1);
  __syncthreads();
  COMPUTE(0);
  WRITEK(1);
  __syncthreads();
  COMPUTE(1);

  // ---- fused LayerNorm(64) + leaky + mask epilogue ----
  // channel c = mf*16 + (lane>>4)*4 + r ; voxel = n0+wn+nf*16+(lane&15)
  float gr[4][4], br_[4][4];
#pragma unroll
  for (int mf = 0; mf < 4; ++mf) {
    int cb = mf * 16 + ((lane >> 4) << 2);
    f32x4 gv = *reinterpret_cast<const f32x4*>(gamma + cb);
    f32x4 bv = *reinterpret_cast<const f32x4*>(beta + cb);
#pragma unroll
    for (int r = 0; r < 4; ++r) { gr[mf][r] = gv[r]; br_[mf][r] = bv[r]; }
  }

#pragma unroll
  for (int nf = 0; nf < 2; ++nf) {
    float s = 0.f, sq = 0.f;
#pragma unroll
    for (int mf = 0; mf < 4; ++mf)
#pragma unroll
      for (int r = 0; r < 4; ++r) {
        float v = acc[mf][nf][r];
        s += v; sq += v * v;
      }
    s  += __shfl_xor(s, 16);  sq += __shfl_xor(sq, 16);
    s  += __shfl_xor(s, 32);  sq += __shfl_xor(sq, 32);
    const float mean = s * (1.f / 64.f);
    const float var  = sq * (1.f / 64.f) - mean * mean;
    const float rstd = rsqrtf(var + EPS);
    const int vox = n0 + wn + nf * 16 + (lane & 15);
    const float mk = msk[vox] ? 1.f : 0.f;
#pragma unroll
    for (int mf = 0; mf < 4; ++mf) {
      uint2 u;
      float r0 = (acc[mf][nf][0] - mean) * rstd * gr[mf][0] + br_[mf][0];
      float r1 = (acc[mf][nf][1] - mean) * rstd * gr[mf][1] + br_[mf][1];
      float r2 = (acc[mf][nf][2] - mean) * rstd * gr[mf][2] + br_[mf][2];
      float r3 = (acc[mf][nf][3] - mean) * rstd * gr[mf][3] + br_[mf][3];
      r0 = (r0 > 0.f ? r0 : SLOPE * r0) * mk;
      r1 = (r1 > 0.f ? r1 : SLOPE * r1) * mk;
      r2 = (r2 > 0.f ? r2 : SLOPE * r2) * mk;
      r3 = (r3 > 0.f ? r3 : SLOPE * r3) * mk;
      u.x = ((uint)f2bf(r1) << 16) | (uint)f2bf(r0);
      u.y = ((uint)f2bf(r3) << 16) | (uint)f2bf(r2);
      *reinterpret_cast<uint2*>(out + (size_t)vox * 64 + mf * 16 +
                                ((lane >> 4) << 2)) = u;
    }
  }
}

// ---------------------------------------------------------------------------
// Implicit-GEMM conv (blocks 2-4), 128x128 tile, BK=64, split-K support.
// ---------------------------------------------------------------------------
template <int CIN, int COUT, int DIN, int S, int L2CIN, int SPLITK>
__global__ __launch_bounds__(256) void conv_gemm(
    const ushort* __restrict__ in,
    const ushort* __restrict__ wbf,
    float* __restrict__ rawout,
    const ushort* __restrict__ zpage)
{
  constexpr int W  = DIN / S;
  constexpr int K  = 27 * CIN;
  constexpr int NT = K / 64;
  constexpr int NTS = NT / SPLITK;
  constexpr int LW = (W == 32) ? 5 : (W == 16) ? 4 : 3;
  constexpr size_t NVOX = (size_t)2 * W * W * W;

  const int t    = threadIdx.x;
  const int lane = t & 63;
  const int wave = t >> 6;
  const int n0   = blockIdx.x * 128;
  const int m0   = blockIdx.y * 128;
  const int kb0  = blockIdx.z * NTS;
  float* rawp = rawout + (size_t)blockIdx.z * NVOX * COUT;

  __shared__ short As[2][128 * 64];
  __shared__ short Bs[2][128 * 64];

  int zb[4], yb[4], xb[4], kc8[4], swz[4];
  size_t bb[4];
  const ushort* aptr[4];
#pragma unroll
  for (int j = 0; j < 4; ++j) {
    int q  = t + 256 * j;
    int nl = q >> 3, kc = q & 7;
    kc8[j] = kc * 8;
    swz[j] = nl * 64 + ((kc ^ (nl & 7)) << 3);
    int ng = n0 + nl;
    int xo = ng & (W - 1), yo = (ng >> LW) & (W - 1),
        zo = (ng >> (2 * LW)) & (W - 1), b = ng >> (3 * LW);
    xb[j] = xo * S; yb[j] = yo * S; zb[j] = zo * S;
    bb[j] = (size_t)b * CIN * DIN * DIN * DIN;
    aptr[j] = wbf + (size_t)(m0 + nl) * K + kc * 8;
  }

  short8 ar[4], br[4];

  auto LOADK = [&](int kb) {
    const int off = (kb * 64) >> L2CIN;
    const int ci0 = (kb * 64) & (CIN - 1);
    const int dz = off / 9, rr = off % 9;
    const int dy = rr / 3, dx = rr % 3;
#pragma unroll
    for (int j = 0; j < 4; ++j) {
      ar[j] = *reinterpret_cast<const short8*>(aptr[j] + kb * 64);
      int zin = zb[j] + dz - 1;
      int yin = yb[j] + dy - 1;
      int xin = xb[j] + dx - 1;
      bool ok = ((unsigned)zin < (unsigned)DIN) &&
                ((unsigned)yin < (unsigned)DIN) &&
                ((unsigned)xin < (unsigned)DIN);
      const ushort* p = ok
          ? in + bb[j] + (((size_t)zin * DIN + yin) * DIN + xin) * CIN + ci0 + kc8[j]
          : zpage;
      br[j] = *reinterpret_cast<const short8*>(p);
    }
  };

  auto WRITEK = [&](int buf) {
#pragma unroll
    for (int j = 0; j < 4; ++j) {
      *reinterpret_cast<short8*>(&As[buf][swz[j]]) = ar[j];
      *reinterpret_cast<short8*>(&Bs[buf][swz[j]]) = br[j];
    }
  };

  f32x4 acc[4][4];
#pragma unroll
  for (int i = 0; i < 4; ++i)
#pragma unroll
    for (int j = 0; j < 4; ++j) acc[i][j] = (f32x4)(0.f);

  const int wm = (wave & 1) * 64;
  const int wn = (wave >> 1) * 64;

  LOADK(kb0);
  for (int kb = kb0; kb < kb0 + NTS; ++kb) {
    const int buf = (kb - kb0) & 1;
    WRITEK(buf);
    if (kb + 1 < kb0 + NTS) LOADK(kb + 1);
    __syncthreads();

    short8 afr[4][2], bfr[4][2];
#pragma unroll
    for (int mf = 0; mf < 4; ++mf)
#pragma unroll
      for (int kh = 0; kh < 2; ++kh) {
        int row  = wm + mf * 16 + (lane & 15);
        int slot = (lane >> 4) + kh * 4;
        afr[mf][kh] = *reinterpret_cast<const short8*>(
            &As[buf][row * 64 + ((slot ^ (row & 7)) << 3)]);
      }
#pragma unroll
    for (int nf = 0; nf < 4; ++nf)
#pragma unroll
      for (int kh = 0; kh < 2; ++kh) {
        int row  = wn + nf * 16 + (lane & 15);
        int slot = (lane >> 4) + kh * 4;
        bfr[nf][kh] = *reinterpret_cast<const short8*>(
            &Bs[buf][row * 64 + ((slot ^ (row & 7)) << 3)]);
      }
#pragma unroll
    for (int mf = 0; mf < 4; ++mf)
#pragma unroll
      for (int nf = 0; nf < 4; ++nf)
#pragma unroll
        for (int kh = 0; kh < 2; ++kh)
          acc[mf][nf] = __builtin_amdgcn_mfma_f32_16x16x32_bf16(
              afr[mf][kh], bfr[nf][kh], acc[mf][nf], 0, 0, 0);
  }

#pragma unroll
  for (int mf = 0; mf < 4; ++mf)
#pragma unroll
    for (int nf = 0; nf < 4; ++nf) {
      int mg = m0 + wm + mf * 16 + ((lane >> 4) << 2);
      int ng = n0 + wn + nf * 16 + (lane & 15);
      *reinterpret_cast<f32x4*>(&rawp[(size_t)ng * COUT + mg]) = acc[mf][nf];
    }
}

// ---------------------------------------------------------------------------
// LayerNorm + LeakyReLU + mask on channels-last raw f32 (sums NPART split-K
// partials first). One wave per voxel.
// ---------------------------------------------------------------------------
template <int C, int NPART, bool BF16OUT>
__global__ __launch_bounds__(256) void ln_mask_k(
    const float* __restrict__ raw,       // [NPART][nvox][C]
    const float* __restrict__ gamma,
    const float* __restrict__ beta,
    const uint8_t* __restrict__ msk,
    void* __restrict__ outv, int nvox)
{
  constexpr int E = C / 64;
  const int lane = threadIdx.x & 63;
  const int vox  = blockIdx.x * 4 + (threadIdx.x >> 6);
  if (vox >= nvox) return;

  const size_t stride = (size_t)nvox * C;
  const float* p = raw + (size_t)vox * C;
  float v[E];
  float s = 0.f, sq = 0.f;
#pragma unroll
  for (int e = 0; e < E; ++e) {
    float acc = 0.f;
#pragma unroll
    for (int pt = 0; pt < NPART; ++pt) acc += p[pt * stride + e * 64 + lane];
    v[e] = acc;
    s += acc; sq += acc * acc;
  }
#pragma unroll
  for (int off = 32; off; off >>= 1) {
    s  += __shfl_xor(s, off);
    sq += __shfl_xor(sq, off);
  }
  const float mean = s / (float)C;
  const float var  = sq / (float)C - mean * mean;
  const float rstd = rsqrtf(var + EPS);
  const float mk   = msk[vox] ? 1.f : 0.f;

#pragma unroll
  for (int e = 0; e < E; ++e) {
    int c = e * 64 + lane;
    float r = (v[e] - mean) * rstd * gamma[c] + beta[c];
    r = (r > 0.f ? r : SLOPE * r) * mk;
    if (BF16OUT)
      ((ushort*)outv)[(size_t)vox * C + c] = f2bf(r);
    else
      ((float*)outv)[(size_t)vox * C + c] = r;
  }
}

// t4 [2*512 vox][512 c] f32 -> partial max over 64-voxel groups
__global__ void rmax1_k(const float* __restrict__ t4, float* __restrict__ pm) {
  const int g = blockIdx.x;
  const int b = blockIdx.y;
  const int c = threadIdx.x;
  float m = -1e30f;
  for (int v = g * 64; v < g * 64 + 64; ++v)
    m = fmaxf(m, t4[((size_t)(b * 512 + v)) * 512 + c]);
  pm[((size_t)b * 8 + g) * 512 + c] = m;
}

__global__ void rmax2_k(const float* __restrict__ pm, float* __restrict__ out) {
  const int b = blockIdx.x;
  const int c = threadIdx.x;
  float m = -1e30f;
  for (int g = 0; g < 8; ++g) m = fmaxf(m, pm[((size_t)b * 8 + g) * 512 + c]);
  out[b * 512 + c] = m;
}

// ---------------------------------------------------------------------------
extern "C" void kernel_launch(void* const* d_in, const int* in_sizes, int n_in,
                              void* d_out, int out_size, void* d_ws, size_t ws_size,
                              hipStream_t stream) {
  const float*   x    = (const float*)d_in[0];
  const uint8_t* mraw = (const uint8_t*)d_in[1];
  const float* w1 = (const float*)d_in[2];
  const float* g1 = (const float*)d_in[3];
  const float* b1 = (const float*)d_in[4];
  const float* w2 = (const float*)d_in[5];
  const float* g2 = (const float*)d_in[6];
  const float* b2 = (const float*)d_in[7];
  const float* w3 = (const float*)d_in[8];
  const float* g3 = (const float*)d_in[9];
  const float* b3 = (const float*)d_in[10];
  const float* w4 = (const float*)d_in[11];
  const float* g4 = (const float*)d_in[12];
  const float* b4 = (const float*)d_in[13];
  float* out = (float*)d_out;
  char*  ws  = (char*)d_ws;

  // ---- workspace layout (bytes); r3/r4 alias r2 (dead after ln b2) ----
  const size_t ZP  = 0;                      // flag@0, zero-page@16
  const size_t T1  = 256;                    // 67,108,864  bf16 CL [524288][64]
  const size_t R2  = 67109120;               // 33,554,432  f32 [65536][128]
  const size_t R3  = R2;                     // 16,777,216  f32 [2][8192][256]
  const size_t R4  = R2 + 16777216;          //  8,388,608  f32 [4][1024][512]
  const size_t T2  = 100663552;              // 16,777,216  bf16 [65536][128]
  const size_t T3  = 117440768;              //  4,194,304  bf16 [8192][256]
  const size_t T4  = 121635072;              //  2,097,152  f32 [1024][512]
  const size_t PM  = 123732224;              //     32,768
  const size_t XCL = 123764992;              //  4,194,304  bf16 [524288][4]
  const size_t WB1 = 127959296;              //     16,384
  const size_t WB2 = 127975680;              //    442,368
  const size_t WB3 = 128418048;              //  1,769,472
  const size_t WB4 = 130187520;              //  7,077,888
  const size_t M1  = 137265408;              //    524,288
  const size_t M2  = 137789696;              //     65,536
  const size_t M3  = 137855232;              //      8,192
  const size_t M4  = 137863424;              //      1,024

  unsigned* flag = (unsigned*)(ws + ZP);
  const ushort* zpage = (const ushort*)(ws + ZP + 16);
  ushort* t1  = (ushort*)(ws + T1);
  float*  r2  = (float*)(ws + R2);
  float*  r3  = (float*)(ws + R3);
  float*  r4  = (float*)(ws + R4);
  ushort* t2  = (ushort*)(ws + T2);
  ushort* t3  = (ushort*)(ws + T3);
  float*  t4  = (float*)(ws + T4);
  float*  pm  = (float*)(ws + PM);
  ushort* xcl = (ushort*)(ws + XCL);
  ushort* wb1 = (ushort*)(ws + WB1);
  ushort* wb2 = (ushort*)(ws + WB2);
  ushort* wb3 = (ushort*)(ws + WB3);
  ushort* wb4 = (ushort*)(ws + WB4);
  uint8_t* m1 = (uint8_t*)(ws + M1);
  uint8_t* m2 = (uint8_t*)(ws + M2);
  uint8_t* m3 = (uint8_t*)(ws + M3);
  uint8_t* m4 = (uint8_t*)(ws + M4);

  const int NM1 = 2 * 64 * 64 * 64;

  hipMemsetAsync(ws + ZP, 0, 64, stream);
  mask_detect_k<<<256, 256, 0, stream>>>(mraw, NM1, flag);
  mask_convert_k<<<(NM1 + 255) / 256, 256, 0, stream>>>(mraw, flag, m1, NM1);
  mask_down_k<<<(2 * 32 * 32 * 32 + 255) / 256, 256, 0, stream>>>(m1, m2, 64);
  mask_down_k<<<(2 * 16 * 16 * 16 + 255) / 256, 256, 0, stream>>>(m2, m3, 32);
  mask_down_k<<<(2 * 8 * 8 * 8 + 255) / 256, 256, 0, stream>>>(m3, m4, 16);

  wb1_k<<<(64 * 128 + 255) / 256, 256, 0, stream>>>(w1, wb1);
  wbf_k<<<(128 * 1728 + 255) / 256, 256, 0, stream>>>(w2, wb2, 128, 64);
  wbf_k<<<(256 * 3456 + 255) / 256, 256, 0, stream>>>(w3, wb3, 256, 128);
  wbf_k<<<(512 * 6912 + 255) / 256, 256, 0, stream>>>(w4, wb4, 512, 256);

  // block1: pre-pack + MFMA GEMM with fused LN/leaky/mask -> t1 bf16 CL
  xcl_k<<<(NM1 + 255) / 256, 256, 0, stream>>>(x, m1, xcl);
  conv1_gemm<<<4096, 256, 0, stream>>>(xcl, wb1, g1, b1, m1, t1);

  // block2: 64->128, s2
  conv_gemm<64, 128, 64, 2, 6, 1><<<dim3(512, 1, 1), 256, 0, stream>>>(t1, wb2, r2, zpage);
  ln_mask_k<128, 1, true><<<65536 / 4, 256, 0, stream>>>(r2, g2, b2, m2, t2, 65536);

  // block3: 128->256, s2, split-K 2
  conv_gemm<128, 256, 32, 2, 7, 2><<<dim3(64, 2, 2), 256, 0, stream>>>(t2, wb3, r3, zpage);
  ln_mask_k<256, 2, true><<<8192 / 4, 256, 0, stream>>>(r3, g3, b3, m3, t3, 8192);

  // block4: 256->512, s2, split-K 4
  conv_gemm<256, 512, 16, 2, 8, 4><<<dim3(8, 4, 4), 256, 0, stream>>>(t3, wb4, r4, zpage);
  ln_mask_k<512, 4, false><<<1024 / 4, 256, 0, stream>>>(r4, g4, b4, m4, t4, 1024);

  rmax1_k<<<dim3(8, 2), 512, 0, stream>>>(t4, pm);
  rmax2_k<<<2, 512, 0, stream>>>(pm, out);

  (void)in_sizes; (void)n_in; (void)out_size; (void)ws_size;
}

// Round 4
// 203.650 us; speedup vs baseline: 10.8384x; 1.0866x over previous
//
#include <hip/hip_runtime.h>
#include <hip/hip_bf16.h>
#include <stdint.h>

#define EPS 1e-5f
#define SLOPE 0.2f

typedef __attribute__((ext_vector_type(8))) short short8;
typedef __attribute__((ext_vector_type(4))) float f32x4;

static __device__ inline ushort f2bf(float f) {
  __hip_bfloat16 h = __float2bfloat16(f);
  return *reinterpret_cast<ushort*>(&h);
}

static __device__ inline short8 u4_to_s8(uint a, uint b, uint c, uint d) {
  union { uint4 u; short8 s; } cv;
  cv.u.x = a; cv.u.y = b; cv.u.z = c; cv.u.w = d;
  return cv.s;
}

// ---------------------------------------------------------------------------
// Mask dtype detection (bool vs 4-byte layout).
// ---------------------------------------------------------------------------
__global__ void mask_detect_k(const uint8_t* __restrict__ raw, int nbytes,
                              unsigned* __restrict__ flag) {
  unsigned local = 0;
  for (int i = blockIdx.x * blockDim.x + threadIdx.x; i < nbytes;
       i += gridDim.x * blockDim.x)
    if (i & 3) local |= raw[i];
  if (local) atomicOr(flag, 1u);
}

// Fused mask-convert + input pack: m1[id] and xcl[id][4] (masked bf16, ci3=0)
__global__ void xclm_k(const float* __restrict__ x, const uint8_t* __restrict__ raw,
                       const unsigned* __restrict__ flag,
                       uint8_t* __restrict__ m1, ushort* __restrict__ xcl) {
  int id = blockIdx.x * blockDim.x + threadIdx.x;
  if (id >= 2 * 262144) return;
  uint8_t v;
  if (*flag) {
    v = raw[id];
  } else {
    size_t j = 4 * (size_t)id;
    v = (uint8_t)(raw[j] | raw[j + 1] | raw[j + 2] | raw[j + 3]);
  }
  v = v ? 1 : 0;
  m1[id] = v;
  float mk = (float)v;
  int b  = id >> 18;
  int sp = id & 262143;
  size_t base = (size_t)b * 3 * 262144 + sp;
  float x0 = x[base] * mk;
  float x1 = x[base + 262144] * mk;
  float x2 = x[base + 2 * 262144] * mk;
  uint2 u;
  u.x = ((uint)f2bf(x1) << 16) | (uint)f2bf(x0);
  u.y = (uint)f2bf(x2);
  *reinterpret_cast<uint2*>(xcl + (size_t)id * 4) = u;
}

__global__ void mask_down_k(const uint8_t* __restrict__ mi,
                            uint8_t* __restrict__ mo, int DIN) {
  int W = DIN >> 1;
  int id = blockIdx.x * blockDim.x + threadIdx.x;
  int total = 2 * W * W * W;
  if (id >= total) return;
  int xo = id % W; int t = id / W;
  int yo = t % W;  t /= W;
  int zo = t % W;  int b = t / W;
  int any = 0;
  for (int dz = 0; dz < 3; ++dz) {
    int z = 2 * zo + dz - 1; if (z < 0 || z >= DIN) continue;
    for (int dy = 0; dy < 3; ++dy) {
      int y = 2 * yo + dy - 1; if (y < 0 || y >= DIN) continue;
      for (int dx = 0; dx < 3; ++dx) {
        int x = 2 * xo + dx - 1; if (x < 0 || x >= DIN) continue;
        any |= mi[(((size_t)b * DIN + z) * DIN + y) * DIN + x];
      }
    }
  }
  mo[id] = any ? 1 : 0;
}

// ---------------------------------------------------------------------------
// All weight preps fused. wb1: w1[64][3][27] -> [64][128] (k=tap*4+ci, padded).
// wb2/3/4: w[c][ci*27+off] -> wb[c][off*CIN+ci] bf16.
// ---------------------------------------------------------------------------
__global__ void wprep_k(const float* __restrict__ w1, const float* __restrict__ w2,
                        const float* __restrict__ w3, const float* __restrict__ w4,
                        ushort* __restrict__ wb1, ushort* __restrict__ wb2,
                        ushort* __restrict__ wb3, ushort* __restrict__ wb4) {
  int id = blockIdx.x * blockDim.x + threadIdx.x;
  if (id < 8192) {
    int k = id & 127, c = id >> 7;
    int tap = k >> 2, ci = k & 3;
    float v = (tap < 27 && ci < 3) ? w1[c * 81 + ci * 27 + tap] : 0.f;
    wb1[id] = f2bf(v);
    return;
  }
  id -= 8192;
  if (id < 128 * 1728) {
    int kn = id % 1728, c = id / 1728;
    int off = kn >> 6, ci = kn & 63;
    wb2[(size_t)c * 1728 + kn] = f2bf(w2[(size_t)c * 1728 + ci * 27 + off]);
    return;
  }
  id -= 128 * 1728;
  if (id < 256 * 3456) {
    int kn = id % 3456, c = id / 3456;
    int off = kn >> 7, ci = kn & 127;
    wb3[(size_t)c * 3456 + kn] = f2bf(w3[(size_t)c * 3456 + ci * 27 + off]);
    return;
  }
  id -= 256 * 3456;
  if (id < 512 * 6912) {
    int kn = id % 6912, c = id / 6912;
    int off = kn >> 8, ci = kn & 255;
    wb4[(size_t)c * 6912 + kn] = f2bf(w4[(size_t)c * 6912 + ci * 27 + off]);
  }
}

// ---------------------------------------------------------------------------
// Block1 implicit GEMM: M=64, N=524288, K=128 (32 taps x 4ci, zero-padded).
// B staging: nl = t&127 (one voxel/thread), kc = (t>>7)+2j -> coalesced
// same-tap gathers with uniform tap offsets. Fused LN+leaky+mask epilogue.
// ---------------------------------------------------------------------------
__global__ __launch_bounds__(256) void conv1_gemm(
    const ushort* __restrict__ xcl,     // [2*64^3][4] bf16
    const ushort* __restrict__ wb1,     // [64][128] bf16
    const float* __restrict__ gamma,
    const float* __restrict__ beta,
    const uint8_t* __restrict__ msk,    // [2*64^3]
    ushort* __restrict__ out,           // [2*64^3][64] bf16
    const ushort* __restrict__ zpage)
{
  const int t    = threadIdx.x;
  const int lane = t & 63;
  const int wave = t >> 6;
  int bid = blockIdx.x;
  bid = (bid & 7) * 512 + (bid >> 3);       // XCD swizzle (4096 = 8*512)
  const int n0 = bid * 128;
  const int wn = wave * 32;

  __shared__ short As[2][64 * 64];
  __shared__ short Bs[2][128 * 64];

  // B: one voxel per thread
  const int nl   = t & 127;
  const int kchi = t >> 7;
  const int ng = n0 + nl;
  const int bx = ng & 63, by = (ng >> 6) & 63, bz = (ng >> 12) & 63;
  const long basevox = (long)ng * 4;
  const bool okx0 = bx > 0, okx2 = bx < 63;
  const bool oky0 = by > 0, oky2 = by < 63;
  const bool okz0 = bz > 0, okz2 = bz < 63;
  int bswz[4];
#pragma unroll
  for (int j = 0; j < 4; ++j) {
    int kc = kchi + 2 * j;
    bswz[j] = nl * 64 + ((kc ^ (nl & 7)) << 3);
  }
  // A: 2 tasks, row-contiguous mapping
  int aswz[2];
  const ushort* aptr[2];
#pragma unroll
  for (int j = 0; j < 2; ++j) {
    int q = t + 256 * j, ml = q >> 3, kc = q & 7;
    aswz[j] = ml * 64 + ((kc ^ (ml & 7)) << 3);
    aptr[j] = wb1 + ml * 128 + kc * 8;
  }

  short8 ar[2], br[4];

  auto LOADK = [&](int kb) {
#pragma unroll
    for (int j = 0; j < 2; ++j)
      ar[j] = *reinterpret_cast<const short8*>(aptr[j] + kb * 64);
#pragma unroll
    for (int j = 0; j < 4; ++j) {
      int tp0 = kb * 16 + (kchi + 2 * j) * 2;
      uint wrd[4];
#pragma unroll
      for (int h = 0; h < 2; ++h) {
        int tp = tp0 + h;
        int dz = tp / 9, rr = tp - dz * 9;
        int dy = rr / 3, dx = rr - dy * 3;
        bool ok = (tp < 27)
               && (dz != 0 || okz0) && (dz != 2 || okz2)
               && (dy != 0 || oky0) && (dy != 2 || oky2)
               && (dx != 0 || okx0) && (dx != 2 || okx2);
        long toff = (long)(((dz - 1) * 4096 + (dy - 1) * 64 + (dx - 1)) * 4);
        const ushort* p = ok ? (xcl + basevox + toff) : zpage;
        uint2 v = *reinterpret_cast<const uint2*>(p);
        wrd[2 * h] = v.x; wrd[2 * h + 1] = v.y;
      }
      br[j] = u4_to_s8(wrd[0], wrd[1], wrd[2], wrd[3]);
    }
  };

  auto WRITEK = [&](int buf) {
#pragma unroll
    for (int j = 0; j < 2; ++j)
      *reinterpret_cast<short8*>(&As[buf][aswz[j]]) = ar[j];
#pragma unroll
    for (int j = 0; j < 4; ++j)
      *reinterpret_cast<short8*>(&Bs[buf][bswz[j]]) = br[j];
  };

  f32x4 acc[4][2];
#pragma unroll
  for (int i = 0; i < 4; ++i)
#pragma unroll
    for (int j = 0; j < 2; ++j) acc[i][j] = (f32x4)(0.f);

  auto COMPUTE = [&](int buf) {
    short8 afr[4][2], bfr[2][2];
#pragma unroll
    for (int mf = 0; mf < 4; ++mf)
#pragma unroll
      for (int kh = 0; kh < 2; ++kh) {
        int row  = mf * 16 + (lane & 15);
        int slot = (lane >> 4) + kh * 4;
        afr[mf][kh] = *reinterpret_cast<const short8*>(
            &As[buf][row * 64 + ((slot ^ (row & 7)) << 3)]);
      }
#pragma unroll
    for (int nf = 0; nf < 2; ++nf)
#pragma unroll
      for (int kh = 0; kh < 2; ++kh) {
        int row  = wn + nf * 16 + (lane & 15);
        int slot = (lane >> 4) + kh * 4;
        bfr[nf][kh] = *reinterpret_cast<const short8*>(
            &Bs[buf][row * 64 + ((slot ^ (row & 7)) << 3)]);
      }
#pragma unroll
    for (int mf = 0; mf < 4; ++mf)
#pragma unroll
      for (int nf = 0; nf < 2; ++nf)
#pragma unroll
        for (int kh = 0; kh < 2; ++kh)
          acc[mf][nf] = __builtin_amdgcn_mfma_f32_16x16x32_bf16(
              afr[mf][kh], bfr[nf][kh], acc[mf][nf], 0, 0, 0);
  };

  LOADK(0);
  WRITEK(0);
  LOADK(1);
  __syncthreads();
  COMPUTE(0);
  WRITEK(1);
  __syncthreads();
  COMPUTE(1);

  // ---- fused LayerNorm(64) + leaky + mask epilogue ----
  float gr[4][4], br_[4][4];
#pragma unroll
  for (int mf = 0; mf < 4; ++mf) {
    int cb = mf * 16 + ((lane >> 4) << 2);
    f32x4 gv = *reinterpret_cast<const f32x4*>(gamma + cb);
    f32x4 bv = *reinterpret_cast<const f32x4*>(beta + cb);
#pragma unroll
    for (int r = 0; r < 4; ++r) { gr[mf][r] = gv[r]; br_[mf][r] = bv[r]; }
  }

#pragma unroll
  for (int nf = 0; nf < 2; ++nf) {
    float s = 0.f, sq = 0.f;
#pragma unroll
    for (int mf = 0; mf < 4; ++mf)
#pragma unroll
      for (int r = 0; r < 4; ++r) {
        float v = acc[mf][nf][r];
        s += v; sq += v * v;
      }
    s  += __shfl_xor(s, 16);  sq += __shfl_xor(sq, 16);
    s  += __shfl_xor(s, 32);  sq += __shfl_xor(sq, 32);
    const float mean = s * (1.f / 64.f);
    const float var  = sq * (1.f / 64.f) - mean * mean;
    const float rstd = rsqrtf(var + EPS);
    const int vox = n0 + wn + nf * 16 + (lane & 15);
    const float mk = msk[vox] ? 1.f : 0.f;
#pragma unroll
    for (int mf = 0; mf < 4; ++mf) {
      uint2 u;
      float r0 = (acc[mf][nf][0] - mean) * rstd * gr[mf][0] + br_[mf][0];
      float r1 = (acc[mf][nf][1] - mean) * rstd * gr[mf][1] + br_[mf][1];
      float r2 = (acc[mf][nf][2] - mean) * rstd * gr[mf][2] + br_[mf][2];
      float r3 = (acc[mf][nf][3] - mean) * rstd * gr[mf][3] + br_[mf][3];
      r0 = (r0 > 0.f ? r0 : SLOPE * r0) * mk;
      r1 = (r1 > 0.f ? r1 : SLOPE * r1) * mk;
      r2 = (r2 > 0.f ? r2 : SLOPE * r2) * mk;
      r3 = (r3 > 0.f ? r3 : SLOPE * r3) * mk;
      u.x = ((uint)f2bf(r1) << 16) | (uint)f2bf(r0);
      u.y = ((uint)f2bf(r3) << 16) | (uint)f2bf(r2);
      *reinterpret_cast<uint2*>(out + (size_t)vox * 64 + mf * 16 +
                                ((lane >> 4) << 2)) = u;
    }
  }
}

// ---------------------------------------------------------------------------
// Block2: implicit GEMM 64->128 s2 with FUSED LN+leaky+mask epilogue
// (COUT=128 = one M-tile, so the block holds the full channel vector).
// Writes bf16 channels-last t2 directly.
// ---------------------------------------------------------------------------
__global__ __launch_bounds__(256) void conv2_gemm(
    const ushort* __restrict__ in,      // t1 [524288][64] bf16
    const ushort* __restrict__ wbf,     // wb2 [128][1728] bf16
    const float* __restrict__ gamma,
    const float* __restrict__ beta,
    const uint8_t* __restrict__ msk,    // m2 [65536]
    ushort* __restrict__ out,           // t2 [65536][128] bf16
    const ushort* __restrict__ zpage)
{
  constexpr int CIN = 64, DIN = 64, S = 2;
  constexpr int W = 32, K = 1728, NT = 27, LW = 5;

  const int t    = threadIdx.x;
  const int lane = t & 63;
  const int wave = t >> 6;
  int bid = blockIdx.x;
  bid = (bid & 7) * 64 + (bid >> 3);        // XCD swizzle (512 = 8*64)
  const int n0 = bid * 128;

  __shared__ short As[2][128 * 64];
  __shared__ short Bs[2][128 * 64];
  __shared__ float lnS[4][4][16];
  __shared__ float lnQ[4][4][16];

  int zb[4], yb[4], xb[4], kc8[4], swz[4];
  size_t bb[4];
  const ushort* aptr[4];
#pragma unroll
  for (int j = 0; j < 4; ++j) {
    int q  = t + 256 * j;
    int nl = q >> 3, kc = q & 7;
    kc8[j] = kc * 8;
    swz[j] = nl * 64 + ((kc ^ (nl & 7)) << 3);
    int ngv = n0 + nl;
    int xo = ngv & (W - 1), yo = (ngv >> LW) & (W - 1),
        zo = (ngv >> (2 * LW)) & (W - 1), b = ngv >> (3 * LW);
    xb[j] = xo * S; yb[j] = yo * S; zb[j] = zo * S;
    bb[j] = (size_t)b * CIN * DIN * DIN * DIN;
    aptr[j] = wbf + (size_t)nl * K + kc * 8;
  }

  short8 ar[4], br[4];

  auto LOADK = [&](int kb) {
    const int off = kb;                      // 64 k = 1 tap (CIN=64)
    const int dz = off / 9, rr = off % 9;
    const int dy = rr / 3, dx = rr % 3;
#pragma unroll
    for (int j = 0; j < 4; ++j) {
      ar[j] = *reinterpret_cast<const short8*>(aptr[j] + kb * 64);
      int zin = zb[j] + dz - 1;
      int yin = yb[j] + dy - 1;
      int xin = xb[j] + dx - 1;
      bool ok = ((unsigned)zin < (unsigned)DIN) &&
                ((unsigned)yin < (unsigned)DIN) &&
                ((unsigned)xin < (unsigned)DIN);
      const ushort* p = ok
          ? in + bb[j] + (((size_t)zin * DIN + yin) * DIN + xin) * CIN + kc8[j]
          : zpage;
      br[j] = *reinterpret_cast<const short8*>(p);
    }
  };

  auto WRITEK = [&](int buf) {
#pragma unroll
    for (int j = 0; j < 4; ++j) {
      *reinterpret_cast<short8*>(&As[buf][swz[j]]) = ar[j];
      *reinterpret_cast<short8*>(&Bs[buf][swz[j]]) = br[j];
    }
  };

  f32x4 acc[4][4];
#pragma unroll
  for (int i = 0; i < 4; ++i)
#pragma unroll
    for (int j = 0; j < 4; ++j) acc[i][j] = (f32x4)(0.f);

  const int wm = (wave & 1) * 64;
  const int wn = (wave >> 1) * 64;

  LOADK(0);
  for (int kb = 0; kb < NT; ++kb) {
    const int buf = kb & 1;
    WRITEK(buf);
    if (kb + 1 < NT) LOADK(kb + 1);
    __syncthreads();

    short8 afr[4][2], bfr[4][2];
#pragma unroll
    for (int mf = 0; mf < 4; ++mf)
#pragma unroll
      for (int kh = 0; kh < 2; ++kh) {
        int row  = wm + mf * 16 + (lane & 15);
        int slot = (lane >> 4) + kh * 4;
        afr[mf][kh] = *reinterpret_cast<const short8*>(
            &As[buf][row * 64 + ((slot ^ (row & 7)) << 3)]);
      }
#pragma unroll
    for (int nf = 0; nf < 4; ++nf)
#pragma unroll
      for (int kh = 0; kh < 2; ++kh) {
        int row  = wn + nf * 16 + (lane & 15);
        int slot = (lane >> 4) + kh * 4;
        bfr[nf][kh] = *reinterpret_cast<const short8*>(
            &Bs[buf][row * 64 + ((slot ^ (row & 7)) << 3)]);
      }
#pragma unroll
    for (int mf = 0; mf < 4; ++mf)
#pragma unroll
      for (int nf = 0; nf < 4; ++nf)
#pragma unroll
        for (int kh = 0; kh < 2; ++kh)
          acc[mf][nf] = __builtin_amdgcn_mfma_f32_16x16x32_bf16(
              afr[mf][kh], bfr[nf][kh], acc[mf][nf], 0, 0, 0);
  }

  // ---- fused LayerNorm(128) + leaky + mask epilogue ----
  float sv[4], qv[4];
#pragma unroll
  for (int nf = 0; nf < 4; ++nf) {
    float s = 0.f, sq = 0.f;
#pragma unroll
    for (int mf = 0; mf < 4; ++mf)
#pragma unroll
      for (int r = 0; r < 4; ++r) {
        float v = acc[mf][nf][r];
        s += v; sq += v * v;
      }
    s  += __shfl_xor(s, 16);  sq += __shfl_xor(sq, 16);
    s  += __shfl_xor(s, 32);  sq += __shfl_xor(sq, 32);
    sv[nf] = s; qv[nf] = sq;
  }
  if (lane < 16) {
#pragma unroll
    for (int nf = 0; nf < 4; ++nf) {
      lnS[wave][nf][lane] = sv[nf];
      lnQ[wave][nf][lane] = qv[nf];
    }
  }
  __syncthreads();

  float gr[4][4], br_[4][4];
#pragma unroll
  for (int mf = 0; mf < 4; ++mf) {
    int cb = wm + mf * 16 + ((lane >> 4) << 2);
    f32x4 gv = *reinterpret_cast<const f32x4*>(gamma + cb);
    f32x4 bv = *reinterpret_cast<const f32x4*>(beta + cb);
#pragma unroll
    for (int r = 0; r < 4; ++r) { gr[mf][r] = gv[r]; br_[mf][r] = bv[r]; }
  }

#pragma unroll
  for (int nf = 0; nf < 4; ++nf) {
    const float s  = sv[nf] + lnS[wave ^ 1][nf][lane & 15];
    const float sq = qv[nf] + lnQ[wave ^ 1][nf][lane & 15];
    const float mean = s * (1.f / 128.f);
    const float var  = sq * (1.f / 128.f) - mean * mean;
    const float rstd = rsqrtf(var + EPS);
    const int vox = n0 + wn + nf * 16 + (lane & 15);
    const float mk = msk[vox] ? 1.f : 0.f;
#pragma unroll
    for (int mf = 0; mf < 4; ++mf) {
      uint2 u;
      float r0 = (acc[mf][nf][0] - mean) * rstd * gr[mf][0] + br_[mf][0];
      float r1 = (acc[mf][nf][1] - mean) * rstd * gr[mf][1] + br_[mf][1];
      float r2 = (acc[mf][nf][2] - mean) * rstd * gr[mf][2] + br_[mf][2];
      float r3 = (acc[mf][nf][3] - mean) * rstd * gr[mf][3] + br_[mf][3];
      r0 = (r0 > 0.f ? r0 : SLOPE * r0) * mk;
      r1 = (r1 > 0.f ? r1 : SLOPE * r1) * mk;
      r2 = (r2 > 0.f ? r2 : SLOPE * r2) * mk;
      r3 = (r3 > 0.f ? r3 : SLOPE * r3) * mk;
      u.x = ((uint)f2bf(r1) << 16) | (uint)f2bf(r0);
      u.y = ((uint)f2bf(r3) << 16) | (uint)f2bf(r2);
      *reinterpret_cast<uint2*>(out + (size_t)vox * 128 + wm + mf * 16 +
                                ((lane >> 4) << 2)) = u;
    }
  }
}

// ---------------------------------------------------------------------------
// Implicit-GEMM conv (blocks 3-4), 128x128 tile, BK=64, split-K.
// ---------------------------------------------------------------------------
template <int CIN, int COUT, int DIN, int S, int L2CIN, int SPLITK>
__global__ __launch_bounds__(256) void conv_gemm(
    const ushort* __restrict__ in,
    const ushort* __restrict__ wbf,
    float* __restrict__ rawout,
    const ushort* __restrict__ zpage)
{
  constexpr int W  = DIN / S;
  constexpr int K  = 27 * CIN;
  constexpr int NT = K / 64;
  constexpr int NTS = NT / SPLITK;
  constexpr int LW = (W == 32) ? 5 : (W == 16) ? 4 : 3;
  constexpr size_t NVOX = (size_t)2 * W * W * W;

  const int t    = threadIdx.x;
  const int lane = t & 63;
  const int wave = t >> 6;
  const int n0   = blockIdx.x * 128;
  const int m0   = blockIdx.y * 128;
  const int kb0  = blockIdx.z * NTS;
  float* rawp = rawout + (size_t)blockIdx.z * NVOX * COUT;

  __shared__ short As[2][128 * 64];
  __shared__ short Bs[2][128 * 64];

  int zb[4], yb[4], xb[4], kc8[4], swz[4];
  size_t bb[4];
  const ushort* aptr[4];
#pragma unroll
  for (int j = 0; j < 4; ++j) {
    int q  = t + 256 * j;
    int nl = q >> 3, kc = q & 7;
    kc8[j] = kc * 8;
    swz[j] = nl * 64 + ((kc ^ (nl & 7)) << 3);
    int ng = n0 + nl;
    int xo = ng & (W - 1), yo = (ng >> LW) & (W - 1),
        zo = (ng >> (2 * LW)) & (W - 1), b = ng >> (3 * LW);
    xb[j] = xo * S; yb[j] = yo * S; zb[j] = zo * S;
    bb[j] = (size_t)b * CIN * DIN * DIN * DIN;
    aptr[j] = wbf + (size_t)(m0 + nl) * K + kc * 8;
  }

  short8 ar[4], br[4];

  auto LOADK = [&](int kb) {
    const int off = (kb * 64) >> L2CIN;
    const int ci0 = (kb * 64) & (CIN - 1);
    const int dz = off / 9, rr = off % 9;
    const int dy = rr / 3, dx = rr % 3;
#pragma unroll
    for (int j = 0; j < 4; ++j) {
      ar[j] = *reinterpret_cast<const short8*>(aptr[j] + kb * 64);
      int zin = zb[j] + dz - 1;
      int yin = yb[j] + dy - 1;
      int xin = xb[j] + dx - 1;
      bool ok = ((unsigned)zin < (unsigned)DIN) &&
                ((unsigned)yin < (unsigned)DIN) &&
                ((unsigned)xin < (unsigned)DIN);
      const ushort* p = ok
          ? in + bb[j] + (((size_t)zin * DIN + yin) * DIN + xin) * CIN + ci0 + kc8[j]
          : zpage;
      br[j] = *reinterpret_cast<const short8*>(p);
    }
  };

  auto WRITEK = [&](int buf) {
#pragma unroll
    for (int j = 0; j < 4; ++j) {
      *reinterpret_cast<short8*>(&As[buf][swz[j]]) = ar[j];
      *reinterpret_cast<short8*>(&Bs[buf][swz[j]]) = br[j];
    }
  };

  f32x4 acc[4][4];
#pragma unroll
  for (int i = 0; i < 4; ++i)
#pragma unroll
    for (int j = 0; j < 4; ++j) acc[i][j] = (f32x4)(0.f);

  const int wm = (wave & 1) * 64;
  const int wn = (wave >> 1) * 64;

  LOADK(kb0);
  for (int kb = kb0; kb < kb0 + NTS; ++kb) {
    const int buf = (kb - kb0) & 1;
    WRITEK(buf);
    if (kb + 1 < kb0 + NTS) LOADK(kb + 1);
    __syncthreads();

    short8 afr[4][2], bfr[4][2];
#pragma unroll
    for (int mf = 0; mf < 4; ++mf)
#pragma unroll
      for (int kh = 0; kh < 2; ++kh) {
        int row  = wm + mf * 16 + (lane & 15);
        int slot = (lane >> 4) + kh * 4;
        afr[mf][kh] = *reinterpret_cast<const short8*>(
            &As[buf][row * 64 + ((slot ^ (row & 7)) << 3)]);
      }
#pragma unroll
    for (int nf = 0; nf < 4; ++nf)
#pragma unroll
      for (int kh = 0; kh < 2; ++kh) {
        int row  = wn + nf * 16 + (lane & 15);
        int slot = (lane >> 4) + kh * 4;
        bfr[nf][kh] = *reinterpret_cast<const short8*>(
            &Bs[buf][row * 64 + ((slot ^ (row & 7)) << 3)]);
      }
#pragma unroll
    for (int mf = 0; mf < 4; ++mf)
#pragma unroll
      for (int nf = 0; nf < 4; ++nf)
#pragma unroll
        for (int kh = 0; kh < 2; ++kh)
          acc[mf][nf] = __builtin_amdgcn_mfma_f32_16x16x32_bf16(
              afr[mf][kh], bfr[nf][kh], acc[mf][nf], 0, 0, 0);
  }

#pragma unroll
  for (int mf = 0; mf < 4; ++mf)
#pragma unroll
    for (int nf = 0; nf < 4; ++nf) {
      int mg = m0 + wm + mf * 16 + ((lane >> 4) << 2);
      int ng = n0 + wn + nf * 16 + (lane & 15);
      *reinterpret_cast<f32x4*>(&rawp[(size_t)ng * COUT + mg]) = acc[mf][nf];
    }
}

// ---------------------------------------------------------------------------
// LayerNorm + LeakyReLU + mask (sums NPART split-K partials). Wave per voxel.
// ---------------------------------------------------------------------------
template <int C, int NPART, bool BF16OUT>
__global__ __launch_bounds__(256) void ln_mask_k(
    const float* __restrict__ raw,
    const float* __restrict__ gamma,
    const float* __restrict__ beta,
    const uint8_t* __restrict__ msk,
    void* __restrict__ outv, int nvox)
{
  constexpr int E = C / 64;
  const int lane = threadIdx.x & 63;
  const int vox  = blockIdx.x * 4 + (threadIdx.x >> 6);
  if (vox >= nvox) return;

  const size_t stride = (size_t)nvox * C;
  const float* p = raw + (size_t)vox * C;
  float v[E];
  float s = 0.f, sq = 0.f;
#pragma unroll
  for (int e = 0; e < E; ++e) {
    float acc = 0.f;
#pragma unroll
    for (int pt = 0; pt < NPART; ++pt) acc += p[pt * stride + e * 64 + lane];
    v[e] = acc;
    s += acc; sq += acc * acc;
  }
#pragma unroll
  for (int off = 32; off; off >>= 1) {
    s  += __shfl_xor(s, off);
    sq += __shfl_xor(sq, off);
  }
  const float mean = s / (float)C;
  const float var  = sq / (float)C - mean * mean;
  const float rstd = rsqrtf(var + EPS);
  const float mk   = msk[vox] ? 1.f : 0.f;

#pragma unroll
  for (int e = 0; e < E; ++e) {
    int c = e * 64 + lane;
    float r = (v[e] - mean) * rstd * gamma[c] + beta[c];
    r = (r > 0.f ? r : SLOPE * r) * mk;
    if (BF16OUT)
      ((ushort*)outv)[(size_t)vox * C + c] = f2bf(r);
    else
      ((float*)outv)[(size_t)vox * C + c] = r;
  }
}

// ---------------------------------------------------------------------------
// Block4 LN + leaky + mask + per-group max (fuses ln_mask<512,4> + rmax1).
// grid = 16 blocks (b*8+g), each handles 64 voxels; pm[16][512].
// ---------------------------------------------------------------------------
__global__ __launch_bounds__(256) void ln4max_k(
    const float* __restrict__ raw,      // [4][1024][512]
    const float* __restrict__ gamma,
    const float* __restrict__ beta,
    const uint8_t* __restrict__ msk,    // [1024]
    float* __restrict__ pm)             // [16][512]
{
  const int t    = threadIdx.x;
  const int lane = t & 63;
  const int wave = t >> 6;
  const int grp  = blockIdx.x;          // 0..15
  const size_t stride = (size_t)1024 * 512;

  float gg[8], bb_[8];
#pragma unroll
  for (int e = 0; e < 8; ++e) {
    int c = e * 64 + lane;
    gg[e] = gamma[c]; bb_[e] = beta[c];
  }

  float vmax[8];
#pragma unroll
  for (int e = 0; e < 8; ++e) vmax[e] = -1e30f;

  for (int it = 0; it < 16; ++it) {
    const int vox = grp * 64 + wave * 16 + it;
    const float* p = raw + (size_t)vox * 512;
    float v[8];
    float s = 0.f, sq = 0.f;
#pragma unroll
    for (int e = 0; e < 8; ++e) {
      float a = 0.f;
#pragma unroll
      for (int pt = 0; pt < 4; ++pt) a += p[pt * stride + e * 64 + lane];
      v[e] = a; s += a; sq += a * a;
    }
#pragma unroll
    for (int off = 32; off; off >>= 1) {
      s  += __shfl_xor(s, off);
      sq += __shfl_xor(sq, off);
    }
    const float mean = s * (1.f / 512.f);
    const float var  = sq * (1.f / 512.f) - mean * mean;
    const float rstd = rsqrtf(var + EPS);
    const float mk   = msk[vox] ? 1.f : 0.f;
#pragma unroll
    for (int e = 0; e < 8; ++e) {
      float r = (v[e] - mean) * rstd * gg[e] + bb_[e];
      r = (r > 0.f ? r : SLOPE * r) * mk;
      vmax[e] = fmaxf(vmax[e], r);
    }
  }

  __shared__ float red[4][512];
#pragma unroll
  for (int e = 0; e < 8; ++e) red[wave][e * 64 + lane] = vmax[e];
  __syncthreads();
  for (int c = t; c < 512; c += 256) {
    float m = fmaxf(fmaxf(red[0][c], red[1][c]), fmaxf(red[2][c], red[3][c]));
    pm[(size_t)grp * 512 + c] = m;
  }
}

__global__ void rmax2_k(const float* __restrict__ pm, float* __restrict__ out) {
  const int b = blockIdx.x;
  const int c = threadIdx.x;
  float m = -1e30f;
  for (int g = 0; g < 8; ++g) m = fmaxf(m, pm[((size_t)b * 8 + g) * 512 + c]);
  out[b * 512 + c] = m;
}

// ---------------------------------------------------------------------------
extern "C" void kernel_launch(void* const* d_in, const int* in_sizes, int n_in,
                              void* d_out, int out_size, void* d_ws, size_t ws_size,
                              hipStream_t stream) {
  const float*   x    = (const float*)d_in[0];
  const uint8_t* mraw = (const uint8_t*)d_in[1];
  const float* w1 = (const float*)d_in[2];
  const float* g1 = (const float*)d_in[3];
  const float* b1 = (const float*)d_in[4];
  const float* w2 = (const float*)d_in[5];
  const float* g2 = (const float*)d_in[6];
  const float* b2 = (const float*)d_in[7];
  const float* w3 = (const float*)d_in[8];
  const float* g3 = (const float*)d_in[9];
  const float* b3 = (const float*)d_in[10];
  const float* w4 = (const float*)d_in[11];
  const float* g4 = (const float*)d_in[12];
  const float* b4 = (const float*)d_in[13];
  float* out = (float*)d_out;
  char*  ws  = (char*)d_ws;

  // ---- workspace layout (bytes) ----
  const size_t ZP  = 0;                      // flag@0, zero-page@16
  const size_t T1  = 256;                    // 67,108,864  bf16 CL [524288][64]
  const size_t R3  = 67109120;               // 16,777,216  f32 [2][8192][256]
  const size_t R4  = R3 + 16777216;          //  8,388,608  f32 [4][1024][512]
  const size_t T2  = 100663552;              // 16,777,216  bf16 [65536][128]
  const size_t T3  = 117440768;              //  4,194,304  bf16 [8192][256]
  const size_t PM  = 123732224;              //     32,768  f32 [16][512]
  const size_t XCL = 123764992;              //  4,194,304  bf16 [524288][4]
  const size_t WB1 = 127959296;              //     16,384
  const size_t WB2 = 127975680;              //    442,368
  const size_t WB3 = 128418048;              //  1,769,472
  const size_t WB4 = 130187520;              //  7,077,888
  const size_t M1  = 137265408;              //    524,288
  const size_t M2  = 137789696;              //     65,536
  const size_t M3  = 137855232;              //      8,192
  const size_t M4  = 137863424;              //      1,024

  unsigned* flag = (unsigned*)(ws + ZP);
  const ushort* zpage = (const ushort*)(ws + ZP + 16);
  ushort* t1  = (ushort*)(ws + T1);
  float*  r3  = (float*)(ws + R3);
  float*  r4  = (float*)(ws + R4);
  ushort* t2  = (ushort*)(ws + T2);
  ushort* t3  = (ushort*)(ws + T3);
  float*  pm  = (float*)(ws + PM);
  ushort* xcl = (ushort*)(ws + XCL);
  ushort* wb1 = (ushort*)(ws + WB1);
  ushort* wb2 = (ushort*)(ws + WB2);
  ushort* wb3 = (ushort*)(ws + WB3);
  ushort* wb4 = (ushort*)(ws + WB4);
  uint8_t* m1 = (uint8_t*)(ws + M1);
  uint8_t* m2 = (uint8_t*)(ws + M2);
  uint8_t* m3 = (uint8_t*)(ws + M3);
  uint8_t* m4 = (uint8_t*)(ws + M4);

  const int NM1 = 2 * 64 * 64 * 64;

  hipMemsetAsync(ws + ZP, 0, 64, stream);
  mask_detect_k<<<256, 256, 0, stream>>>(mraw, NM1, flag);
  xclm_k<<<NM1 / 256, 256, 0, stream>>>(x, mraw, flag, m1, xcl);
  mask_down_k<<<(2 * 32 * 32 * 32 + 255) / 256, 256, 0, stream>>>(m1, m2, 64);
  mask_down_k<<<(2 * 16 * 16 * 16 + 255) / 256, 256, 0, stream>>>(m2, m3, 32);
  mask_down_k<<<(2 * 8 * 8 * 8 + 255) / 256, 256, 0, stream>>>(m3, m4, 16);

  wprep_k<<<18176, 256, 0, stream>>>(w1, w2, w3, w4, wb1, wb2, wb3, wb4);

  // block1: MFMA GEMM with fused LN/leaky/mask -> t1 bf16 CL
  conv1_gemm<<<4096, 256, 0, stream>>>(xcl, wb1, g1, b1, m1, t1, zpage);

  // block2: 64->128, s2, fused LN epilogue -> t2 bf16 CL
  conv2_gemm<<<512, 256, 0, stream>>>(t1, wb2, g2, b2, m2, t2, zpage);

  // block3: 128->256, s2, split-K 2
  conv_gemm<128, 256, 32, 2, 7, 2><<<dim3(64, 2, 2), 256, 0, stream>>>(t2, wb3, r3, zpage);
  ln_mask_k<256, 2, true><<<8192 / 4, 256, 0, stream>>>(r3, g3, b3, m3, t3, 8192);

  // block4: 256->512, s2, split-K 4
  conv_gemm<256, 512, 16, 2, 8, 4><<<dim3(8, 4, 4), 256, 0, stream>>>(t3, wb4, r4, zpage);
  ln4max_k<<<16, 256, 0, stream>>>(r4, g4, b4, m4, pm);

  rmax2_k<<<2, 512, 0, stream>>>(pm, out);

  (void)in_sizes; (void)n_in; (void)out_size; (void)ws_size;
}